// Round 5
// baseline (708.203 us; speedup 1.0000x reference)
//
#include <hip/hip_runtime.h>
#include <stdint.h>

#define CC 128
#define HH 192
#define WW 512
#define BB 2
#define HW (HH*WW)
#define CHW (CC*HW)
#define TENS (BB*CHW)   // 25165824 elems per [B,C,H,W] tensor

typedef __attribute__((ext_vector_type(8))) short bf16x8;
typedef __attribute__((ext_vector_type(4))) float f32x4;
typedef __attribute__((ext_vector_type(4))) unsigned short u16x4;

__device__ __forceinline__ unsigned short f2bf(float f) {
    union { float f; unsigned u; } v; v.f = f;
    return (unsigned short)((v.u + 0x7FFFu + ((v.u >> 16) & 1u)) >> 16);
}
__device__ __forceinline__ float bf2f(unsigned short u) {
    union { unsigned u; float f; } v; v.u = ((unsigned)u) << 16;
    return v.f;
}
__device__ __forceinline__ uint32_t cvtpk(float lo, float hi) {
    uint32_t r;
    asm("v_cvt_pk_bf16_f32 %0, %1, %2" : "=v"(r) : "v"(lo), "v"(hi));
    return r;
}
__device__ __forceinline__ f32x4 MFMA(bf16x8 a, bf16x8 b, f32x4 c) {
    return __builtin_amdgcn_mfma_f32_16x16x32_bf16(a, b, c, 0, 0, 0);
}

// ---------------- weight cast: dl_w/dr_w [O][C][3][3] -> fragment-linear
// layout [side][tap][ohalf][kk][n_][lane(64)][8] bf16 so dconv B-operands are
// direct coalesced global loads (1 KB per wave-load, L2-resident).
__global__ __launch_bounds__(256) void wcast_k(
    const float* __restrict__ dlw, const float* __restrict__ drw,
    unsigned short* __restrict__ wd)
{
    int i = blockIdx.x * 256 + threadIdx.x;
    if (i >= 2 * 9 * CC * CC) return;
    int e  = i & 7;
    int l  = (i >> 3) & 63;
    int n_ = (i >> 9) & 3;
    int kk = (i >> 11) & 3;
    int oh = (i >> 13) & 1;
    int rest = i >> 14;
    int tap = rest % 9;
    int side = rest / 9;
    int o = oh * 64 + n_ * 16 + (l & 15);
    int c = kk * 32 + (l >> 4) * 8 + e;
    const float* src = side ? drw : dlw;
    wd[i] = f2bf(src[((size_t)o * CC + c) * 9 + tap]);
}

// ---------------- fused LayerNorm + V-GEMM: reads x once.
// outputs: Nt [B,H,W,C] bf16, V^T [B,H,C,W] bf16
__global__ __launch_bounds__(256) void lnv_k(
    const float* __restrict__ xl, const float* __restrict__ xr,
    const float* __restrict__ nlw, const float* __restrict__ nlb,
    const float* __restrict__ nrw, const float* __restrict__ nrb,
    const float* __restrict__ wlp, const float* __restrict__ blp,
    const float* __restrict__ wrp, const float* __restrict__ brp,
    unsigned short* __restrict__ ntl, unsigned short* __restrict__ ntr,
    unsigned short* __restrict__ vlo, unsigned short* __restrict__ vro)
{
    const int side = blockIdx.y;
    const float* x  = side ? xr : xl;
    const float* nw = side ? nrw : nlw;
    const float* nb = side ? nrb : nlb;
    const float* wv = side ? wrp : wlp;
    const float* bv = side ? brp : blp;
    unsigned short* nt = side ? ntr : ntl;
    unsigned short* vo = side ? vro : vlo;
    const int bid = blockIdx.x;
    const int wt = bid & 7, h = (bid >> 3) % HH, b = bid / (8 * HH);
    const int w0 = wt * 64;
    const int t = threadIdx.x;

    __shared__ unsigned short sA[64][136];    // x^T tile [w][c] bf16
    __shared__ unsigned short sB[128][136];   // weight [o][c] bf16
    __shared__ float red[8][64];
    __shared__ float smu[64], srs[64];

    {
        const int w = t & 63, cg = t >> 6;
        const float* xp = x + (size_t)b * CHW + (size_t)h * WW + w0 + w;
        float s = 0.f, q = 0.f;
        for (int i = 0; i < 16; i++) {
            int c = cg * 32 + i * 2;
            float v0 = xp[(size_t)c * HW];
            float v1 = xp[(size_t)(c + 1) * HW];
            *(uint32_t*)&sA[w][c] = cvtpk(v0, v1);
            s += v0 + v1; q += v0 * v0 + v1 * v1;
        }
        red[cg][w] = s; red[4 + cg][w] = q;
    }
    for (int it = 0; it < 16; it++) {
        int f = it * 1024 + t * 4;
        int o = f >> 7, c = f & 127;
        float4 v = *(const float4*)(wv + o * CC + c);
        *(uint32_t*)&sB[o][c]     = cvtpk(v.x, v.y);
        *(uint32_t*)&sB[o][c + 2] = cvtpk(v.z, v.w);
    }
    __syncthreads();
    if (t < 64) {
        float S = red[0][t] + red[1][t] + red[2][t] + red[3][t];
        float Q = red[4][t] + red[5][t] + red[6][t] + red[7][t];
        float mu = S * (1.f / CC);
        float var = fmaxf(Q * (1.f / CC) - mu * mu, 0.f);
        smu[t] = mu; srs[t] = rsqrtf(var + 1e-6f);
    }
    __syncthreads();
    {   // LayerNorm output (from bf16 x in sA)
        const int w = t >> 2, c0 = (t & 3) * 32;
        const float mu = smu[w], rs = srs[w];
        unsigned short* np = nt + ((size_t)(b * HH + h) * WW + w0 + w) * CC;
        for (int i = 0; i < 32; i += 2) {
            int c = c0 + i;
            float v0 = (bf2f(sA[w][c]) - mu) * rs * nw[c] + nb[c];
            float v1 = (bf2f(sA[w][c + 1]) - mu) * rs * nw[c + 1] + nb[c + 1];
            *(uint32_t*)&np[c] = cvtpk(v0, v1);
        }
    }
    // V GEMM (reads only; no extra barrier needed)
    const int wid = t >> 6, l = t & 63, lr = l & 15, lg = l >> 4;
    f32x4 acc[8] = {};
    for (int kk = 0; kk < 4; kk++) {
        bf16x8 a = *(const bf16x8*)&sA[wid * 16 + lr][kk * 32 + lg * 8];
#pragma unroll
        for (int n_ = 0; n_ < 8; n_++) {
            bf16x8 bb = *(const bf16x8*)&sB[n_ * 16 + lr][kk * 32 + lg * 8];
            acc[n_] = MFMA(a, bb, acc[n_]);
        }
    }
    unsigned short* vp = vo + ((size_t)(b * HH + h) * CC) * WW + w0;
    for (int n_ = 0; n_ < 8; n_++) {
        int o = n_ * 16 + lr;
        float bias = bv[o];
        uint2 uu;
        uu.x = cvtpk(acc[n_][0] + bias, acc[n_][1] + bias);
        uu.y = cvtpk(acc[n_][2] + bias, acc[n_][3] + bias);
        *(uint2*)&vp[(size_t)o * WW + wid * 16 + lg * 4] = uu;
    }
}

// ---------------- K = dilated 3x3 conv (dilation 4, pad 4) over N -> [B,H,W,C] bf16
// 128-wide output tile; A via LDS, B direct global->reg (fragment-linear, L2-hot).
__global__ __launch_bounds__(256, 3) void dconv_k(
    const unsigned short* __restrict__ ntl, const unsigned short* __restrict__ ntr,
    const unsigned short* __restrict__ wfr,
    const float* __restrict__ dlb, const float* __restrict__ drb,
    unsigned short* __restrict__ klo, unsigned short* __restrict__ kro)
{
    const int side = blockIdx.y;
    const unsigned short* nt = side ? ntr : ntl;
    const unsigned short* wbase = wfr + (size_t)side * 9 * 16384;
    const float* bd = side ? drb : dlb;
    unsigned short* ko = side ? kro : klo;
    // bijective XCD swizzle (1536 = 8*192): consecutive logical ids per XCD
    const int bid0 = blockIdx.x;
    const int lgc = (bid0 & 7) * 192 + (bid0 >> 3);
    const int wt = lgc & 3;
    const int hb = lgc >> 2;          // 0..383
    const int h = hb % HH, b = hb / HH;
    const int w0 = wt * 128;
    const int t = threadIdx.x;
    const int wid = t >> 6, l = t & 63, lr = l & 15, lg = l >> 4;
    const int whalf = wid & 1, ohalf = wid >> 1;

    __shared__ unsigned short sA[136][136];   // one dy-row of N, w0-4 .. w0+131

    f32x4 acc[4][4] = {};   // [g: w-subgroup][n: o-subgroup]
    for (int dy = 0; dy < 3; dy++) {
        const int hh = h + 4 * (dy - 1);
        const bool hok = (hh >= 0 && hh < HH);
        __syncthreads();
        for (int f = t * 8; f < 136 * 128; f += 2048) {
            int wloc = f >> 7, c = f & 127;
            int w = w0 - 4 + wloc;
            bf16x8 v = {0, 0, 0, 0, 0, 0, 0, 0};
            if (hok && w >= 0 && w < WW)
                v = *(const bf16x8*)(nt + ((size_t)(b * HH + hh) * WW + w) * CC + c);
            *(bf16x8*)&sA[wloc][c] = v;
        }
        __syncthreads();
#pragma unroll
        for (int dx = 0; dx < 3; dx++) {
            const unsigned short* wtap =
                wbase + (size_t)(dy * 3 + dx) * 16384 + ohalf * 8192 + l * 8;
#pragma unroll
            for (int kk = 0; kk < 4; kk++) {
                bf16x8 bfr[4];
#pragma unroll
                for (int n_ = 0; n_ < 4; n_++)
                    bfr[n_] = *(const bf16x8*)(wtap + (kk * 4 + n_) * 512);
                bf16x8 af[4];
#pragma unroll
                for (int g = 0; g < 4; g++)
                    af[g] = *(const bf16x8*)&sA[whalf * 64 + g * 16 + lr + 4 * dx][kk * 32 + lg * 8];
#pragma unroll
                for (int g = 0; g < 4; g++)
#pragma unroll
                    for (int n_ = 0; n_ < 4; n_++)
                        acc[g][n_] = MFMA(af[g], bfr[n_], acc[g][n_]);
            }
        }
    }
    unsigned short* kp = ko + ((size_t)(b * HH + h) * WW + w0) * CC;
    for (int g = 0; g < 4; g++)
        for (int n_ = 0; n_ < 4; n_++) {
            int o = ohalf * 64 + n_ * 16 + lr;
            float bias = bd[o];
            for (int j = 0; j < 4; j++) {
                int w = whalf * 64 + g * 16 + lg * 4 + j;
                kp[(size_t)w * CC + o] = f2bf(acc[g][n_][j] + bias);
            }
        }
}

// ---------------- fused Q-GEMM + flash attention (swapped-operand, QBLK=128)
// LDS 51 KB -> 3 blocks/CU. Wq staged in 2 halves; K/V alias dead sQ region.
__global__ __launch_bounds__(256, 3) void attn_k(
    const unsigned short* __restrict__ ntl, const unsigned short* __restrict__ ntr,
    const unsigned short* __restrict__ kl,  const unsigned short* __restrict__ kr,
    const unsigned short* __restrict__ vtl, const unsigned short* __restrict__ vtr,
    const float* __restrict__ lp1w, const float* __restrict__ lp1b,
    const float* __restrict__ rp1w, const float* __restrict__ rp1b,
    const float* __restrict__ xl, const float* __restrict__ xr,
    const float* __restrict__ beta, const float* __restrict__ gamma,
    float* __restrict__ out)
{
    __shared__ __align__(16) char smem[52224];
    unsigned short* sQ  = (unsigned short*)smem;             // [128][136] phase A
    unsigned short* sWh = (unsigned short*)(smem + 34816);   // [64][136]  Wq half
    unsigned short* sKt = (unsigned short*)smem;             // [64][136]  phase B (alias)
    unsigned short* sVt = (unsigned short*)(smem + 17408);   // [128][72]  phase B (alias)

    const int dir = blockIdx.z;
    const unsigned short* nq  = dir ? ntr : ntl;
    const unsigned short* kws = dir ? kl : kr;
    const unsigned short* vws = dir ? vtl : vtr;
    const float* wq   = dir ? rp1w : lp1w;
    const float* bq   = dir ? rp1b : lp1b;
    const float* xres = dir ? xr : xl;
    const float* mult = dir ? gamma : beta;
    float* op = out + (size_t)dir * TENS;

    // XCD-locality swizzle: 4 q-blocks of one bh land consecutively on one XCD
    const int bid = blockIdx.x;
    const int xcd = bid & 7;
    const int s   = bid >> 3;         // 0..191
    const int qb  = s & 3;
    const int bh  = xcd + 8 * (s >> 2);   // 0..383
    const int q0  = qb * 128;
    const int t = threadIdx.x;
    const int wid = t >> 6, l = t & 63, lr = l & 15, lg = l >> 4;

    const unsigned short* ksrc = kws + (size_t)bh * WW * CC;          // [w][c]
    const unsigned short* vsrc = vws + (size_t)bh * CC * WW;          // [c][w]

    // ---- issue K/V tile-0 global loads early (T14) ----
    bf16x8 kreg[4], vreg[4];
#pragma unroll
    for (int it = 0; it < 4; it++) {
        int f = it * 2048 + t * 8;
        kreg[it] = *(const bf16x8*)(ksrc + f);
    }
#pragma unroll
    for (int it = 0; it < 4; it++) {
        int f = it * 2048 + t * 8;
        int c = f >> 6, k = f & 63;
        vreg[it] = *(const bf16x8*)(vsrc + (size_t)c * WW + k);
    }

    // ---- Phase A: stage N tile (128 q-rows); Wq in 2 halves of 64 rows ----
    {
        const unsigned short* nsrc = nq + ((size_t)bh * WW + q0) * CC;
        for (int it = 0; it < 8; it++) {
            int f = it * 2048 + t * 8;
            *(bf16x8*)&sQ[(f >> 7) * 136 + (f & 127)] = *(const bf16x8*)(nsrc + f);
        }
        for (int it = 0; it < 8; it++) {
            int f = it * 1024 + t * 4;
            int o = f >> 7, c = f & 127;
            float4 v = *(const float4*)(wq + o * CC + c);
            *(uint32_t*)&sWh[o * 136 + c]     = cvtpk(v.x, v.y);
            *(uint32_t*)&sWh[o * 136 + c + 2] = cvtpk(v.z, v.w);
        }
    }
    f32x4 qacc[2][8] = {};
    __syncthreads();
    for (int kk = 0; kk < 4; kk++) {
        bf16x8 a0 = *(const bf16x8*)&sQ[(wid * 32 + lr) * 136 + kk * 32 + lg * 8];
        bf16x8 a1 = *(const bf16x8*)&sQ[(wid * 32 + 16 + lr) * 136 + kk * 32 + lg * 8];
#pragma unroll
        for (int n_ = 0; n_ < 4; n_++) {
            bf16x8 b = *(const bf16x8*)&sWh[(n_ * 16 + lr) * 136 + kk * 32 + lg * 8];
            qacc[0][n_] = MFMA(a0, b, qacc[0][n_]);
            qacc[1][n_] = MFMA(a1, b, qacc[1][n_]);
        }
    }
    __syncthreads();
    for (int it = 0; it < 8; it++) {
        int f = it * 1024 + t * 4;
        int o = f >> 7, c = f & 127;
        float4 v = *(const float4*)(wq + (o + 64) * CC + c);
        *(uint32_t*)&sWh[o * 136 + c]     = cvtpk(v.x, v.y);
        *(uint32_t*)&sWh[o * 136 + c + 2] = cvtpk(v.z, v.w);
    }
    __syncthreads();
    for (int kk = 0; kk < 4; kk++) {
        bf16x8 a0 = *(const bf16x8*)&sQ[(wid * 32 + lr) * 136 + kk * 32 + lg * 8];
        bf16x8 a1 = *(const bf16x8*)&sQ[(wid * 32 + 16 + lr) * 136 + kk * 32 + lg * 8];
#pragma unroll
        for (int n_ = 0; n_ < 4; n_++) {
            bf16x8 b = *(const bf16x8*)&sWh[(n_ * 16 + lr) * 136 + kk * 32 + lg * 8];
            qacc[0][4 + n_] = MFMA(a0, b, qacc[0][4 + n_]);
            qacc[1][4 + n_] = MFMA(a1, b, qacc[1][4 + n_]);
        }
    }
    __syncthreads();   // all reads of sQ/sWh done before overwrite
    {
        const float SCL = 0.08838834764831845f * 1.4426950408889634f;  // C^-0.5 * log2e
#pragma unroll
        for (int mg = 0; mg < 2; mg++)
#pragma unroll
            for (int n_ = 0; n_ < 8; n_++) {
                float bias = bq[n_ * 16 + lr];
#pragma unroll
                for (int j = 0; j < 4; j++)
                    sQ[(wid * 32 + mg * 16 + lg * 4 + j) * 136 + n_ * 16 + lr] =
                        f2bf((qacc[mg][n_][j] + bias) * SCL);
            }
    }
    __syncthreads();
    bf16x8 qf[2][4];
#pragma unroll
    for (int qg = 0; qg < 2; qg++)
#pragma unroll
        for (int kk = 0; kk < 4; kk++)
            qf[qg][kk] = *(const bf16x8*)&sQ[(wid * 32 + qg * 16 + lr) * 136 + kk * 32 + lg * 8];

    // ---- Phase B: online-softmax attention, swapped operands ----
    // lane holds P[k=n*16+lg*4+j][q=wid*32+qg*16+lr] -> row-local softmax per qg
    f32x4 oacc[8][2] = {};           // O^T[c=n*16+lg*4+j][q per qg]
    float mrow[2] = {-1e30f, -1e30f};
    float lrow[2] = {0.f, 0.f};
    const int src0 = lr + ((l & 16) << 1);   // lr + 32*(lg&1)
    const int src1 = src0 + 16;
    const int hi = lg >> 1;

    for (int kb = 0; kb < 8; kb++) {
        __syncthreads();   // prior reads of sKt/sVt (or qf loads at kb=0) done
#pragma unroll
        for (int it = 0; it < 4; it++) {
            int f = it * 2048 + t * 8;
            *(bf16x8*)&sKt[(f >> 7) * 136 + (f & 127)] = kreg[it];
        }
#pragma unroll
        for (int it = 0; it < 4; it++) {
            int f = it * 2048 + t * 8;
            int c = f >> 6, k = f & 63;
            *(bf16x8*)&sVt[c * 72 + k] = vreg[it];
        }
        if (kb < 7) {
#pragma unroll
            for (int it = 0; it < 4; it++) {
                int f = it * 2048 + t * 8;
                kreg[it] = *(const bf16x8*)(ksrc + (kb + 1) * 64 * CC + f);
            }
#pragma unroll
            for (int it = 0; it < 4; it++) {
                int f = it * 2048 + t * 8;
                int c = f >> 6, k = f & 63;
                vreg[it] = *(const bf16x8*)(vsrc + (size_t)c * WW + (kb + 1) * 64 + k);
            }
        }
        __syncthreads();
        // QK^T swapped: A = K rows (k), B = Q (col=q); kf read once per (kk,n_)
        f32x4 sacc[2][4] = {};
        __builtin_amdgcn_s_setprio(1);
        for (int kk = 0; kk < 4; kk++)
#pragma unroll
            for (int n_ = 0; n_ < 4; n_++) {
                bf16x8 kf = *(const bf16x8*)&sKt[(n_ * 16 + lr) * 136 + kk * 32 + lg * 8];
                sacc[0][n_] = MFMA(kf, qf[0][kk], sacc[0][n_]);
                sacc[1][n_] = MFMA(kf, qf[1][kk], sacc[1][n_]);
            }
        __builtin_amdgcn_s_setprio(0);
        // tile max per qg
        float pm[2];
#pragma unroll
        for (int qg = 0; qg < 2; qg++) {
            float m_ = sacc[qg][0][0];
#pragma unroll
            for (int n_ = 0; n_ < 4; n_++)
#pragma unroll
                for (int j = 0; j < 4; j++) m_ = fmaxf(m_, sacc[qg][n_][j]);
            m_ = fmaxf(m_, __shfl_xor(m_, 16, 64));
            m_ = fmaxf(m_, __shfl_xor(m_, 32, 64));
            pm[qg] = m_;
        }
        // defer-max (T13): only rescale when max grew by > 8 (log2 units)
        bool need = (pm[0] - mrow[0] > 8.f) || (pm[1] - mrow[1] > 8.f);
        if (__any(need)) {
            float al[2];
#pragma unroll
            for (int qg = 0; qg < 2; qg++) {
                float mn = fmaxf(mrow[qg], pm[qg]);
                al[qg] = exp2f(mrow[qg] - mn);
                mrow[qg] = mn;
                lrow[qg] *= al[qg];
            }
#pragma unroll
            for (int n_ = 0; n_ < 8; n_++)
#pragma unroll
                for (int qg = 0; qg < 2; qg++) {
                    f32x4 o = oacc[n_][qg];
                    o[0] *= al[qg]; o[1] *= al[qg]; o[2] *= al[qg]; o[3] *= al[qg];
                    oacc[n_][qg] = o;
                }
        }
        // exponentials + row-sum (in place: sacc becomes P)
#pragma unroll
        for (int qg = 0; qg < 2; qg++) {
            float rs = 0.f;
#pragma unroll
            for (int n_ = 0; n_ < 4; n_++)
#pragma unroll
                for (int j = 0; j < 4; j++) {
                    float e = exp2f(sacc[qg][n_][j] - mrow[qg]);
                    sacc[qg][n_][j] = e;
                    rs += e;
                }
            rs += __shfl_xor(rs, 16, 64);
            rs += __shfl_xor(rs, 32, 64);
            lrow[qg] += rs;
        }
        // pack P to bf16 pairs: pk[qg][n][word]
        uint32_t pk[2][4][2];
#pragma unroll
        for (int qg = 0; qg < 2; qg++)
#pragma unroll
            for (int n_ = 0; n_ < 4; n_++) {
                pk[qg][n_][0] = cvtpk(sacc[qg][n_][0], sacc[qg][n_][1]);
                pk[qg][n_][1] = cvtpk(sacc[qg][n_][2], sacc[qg][n_][3]);
            }
        // PV swapped: A = V^T rows (c), B = P (col=q); va read once per (kk,n_)
#pragma unroll
        for (int kk = 0; kk < 2; kk++) {
            union { uint32_t u[4]; bf16x8 v; } pf[2];
#pragma unroll
            for (int qg = 0; qg < 2; qg++) {
                uint32_t q00 = __shfl(pk[qg][kk * 2][0],     src0, 64);
                uint32_t q01 = __shfl(pk[qg][kk * 2][1],     src0, 64);
                uint32_t q02 = __shfl(pk[qg][kk * 2][0],     src1, 64);
                uint32_t q03 = __shfl(pk[qg][kk * 2][1],     src1, 64);
                uint32_t q10 = __shfl(pk[qg][kk * 2 + 1][0], src0, 64);
                uint32_t q11 = __shfl(pk[qg][kk * 2 + 1][1], src0, 64);
                uint32_t q12 = __shfl(pk[qg][kk * 2 + 1][0], src1, 64);
                uint32_t q13 = __shfl(pk[qg][kk * 2 + 1][1], src1, 64);
                pf[qg].u[0] = hi ? q10 : q00;
                pf[qg].u[1] = hi ? q11 : q01;
                pf[qg].u[2] = hi ? q12 : q02;
                pf[qg].u[3] = hi ? q13 : q03;
            }
            __builtin_amdgcn_s_setprio(1);
#pragma unroll
            for (int n_ = 0; n_ < 8; n_++) {
                bf16x8 va = *(const bf16x8*)&sVt[(n_ * 16 + lr) * 72 + kk * 32 + lg * 8];
                oacc[n_][0] = MFMA(va, pf[0].v, oacc[n_][0]);
                oacc[n_][1] = MFMA(va, pf[1].v, oacc[n_][1]);
            }
            __builtin_amdgcn_s_setprio(0);
        }
    }

    // ---- epilogue: O^T layout is already [c][w] -> direct coalesced store ----
    const float inv0 = 1.f / lrow[0], inv1 = 1.f / lrow[1];
    const int b = bh / HH, h = bh % HH;
    const int w_0 = q0 + wid * 32 + lr;
    const float* xp0 = xres + (size_t)b * CHW + (size_t)h * WW + w_0;
    float* outp0 = op + (size_t)b * CHW + (size_t)h * WW + w_0;
#pragma unroll
    for (int n_ = 0; n_ < 8; n_++) {
        float4 m4 = *(const float4*)&mult[n_ * 16 + lg * 4];
#pragma unroll
        for (int j = 0; j < 4; j++) {
            int c = n_ * 16 + lg * 4 + j;
            float mj = (&m4.x)[j];
            outp0[(size_t)c * HW]      = xp0[(size_t)c * HW]      + oacc[n_][0][j] * inv0 * mj;
            outp0[(size_t)c * HW + 16] = xp0[(size_t)c * HW + 16] + oacc[n_][1][j] * inv1 * mj;
        }
    }
}

extern "C" void kernel_launch(void* const* d_in, const int* in_sizes, int n_in,
                              void* d_out, int out_size, void* d_ws, size_t ws_size,
                              hipStream_t stream)
{
    const float* xl   = (const float*)d_in[0];
    const float* xr   = (const float*)d_in[1];
    const float* nlw  = (const float*)d_in[2];
    const float* nlb  = (const float*)d_in[3];
    const float* nrw  = (const float*)d_in[4];
    const float* nrb  = (const float*)d_in[5];
    const float* lp1w = (const float*)d_in[6];
    const float* lp1b = (const float*)d_in[7];
    const float* rp1w = (const float*)d_in[8];
    const float* rp1b = (const float*)d_in[9];
    const float* dlw  = (const float*)d_in[10];
    const float* dlb  = (const float*)d_in[11];
    const float* drw  = (const float*)d_in[12];
    const float* drb  = (const float*)d_in[13];
    const float* lp2w = (const float*)d_in[14];
    const float* lp2b = (const float*)d_in[15];
    const float* rp2w = (const float*)d_in[16];
    const float* rp2b = (const float*)d_in[17];
    const float* beta = (const float*)d_in[18];
    const float* gamma= (const float*)d_in[19];
    float* out = (float*)d_out;

    unsigned short* ws = (unsigned short*)d_ws;
    const size_t A = (size_t)TENS;
    unsigned short* Ntl = ws;
    unsigned short* Ntr = ws + A;
    unsigned short* Kl  = ws + 2 * A;
    unsigned short* Kr  = ws + 3 * A;
    unsigned short* Vtl = ws + 4 * A;   // [B,H,C,W]
    unsigned short* Vtr = ws + 5 * A;
    unsigned short* Wd  = ws + 6 * A;   // fragment-linear dconv weights

    wcast_k<<<dim3(1152), 256, 0, stream>>>(dlw, drw, Wd);
    lnv_k<<<dim3(3072, 2), 256, 0, stream>>>(xl, xr, nlw, nlb, nrw, nrb,
        lp2w, lp2b, rp2w, rp2b, Ntl, Ntr, Vtl, Vtr);
    dconv_k<<<dim3(1536, 2), 256, 0, stream>>>(Ntl, Ntr, Wd, dlb, drb, Kl, Kr);
    attn_k<<<dim3(1536, 1, 2), 256, 0, stream>>>(Ntl, Ntr, Kl, Kr, Vtl, Vtr,
        lp1w, lp1b, rp1w, rp1b, xl, xr, beta, gamma, out);
}

// Round 6
// 542.976 us; speedup vs baseline: 1.3043x; 1.3043x over previous
//
#include <hip/hip_runtime.h>
#include <stdint.h>

#define CC 128
#define HH 192
#define WW 512
#define BB 2
#define HW (HH*WW)
#define CHW (CC*HW)
#define TENS (BB*CHW)   // 25165824 elems per [B,C,H,W] tensor

typedef __attribute__((ext_vector_type(8))) short bf16x8;
typedef __attribute__((ext_vector_type(4))) float f32x4;
typedef __attribute__((ext_vector_type(4))) unsigned short u16x4;

__device__ __forceinline__ unsigned short f2bf(float f) {
    union { float f; unsigned u; } v; v.f = f;
    return (unsigned short)((v.u + 0x7FFFu + ((v.u >> 16) & 1u)) >> 16);
}
__device__ __forceinline__ float bf2f(unsigned short u) {
    union { unsigned u; float f; } v; v.u = ((unsigned)u) << 16;
    return v.f;
}
__device__ __forceinline__ uint32_t cvtpk(float lo, float hi) {
    uint32_t r;
    asm("v_cvt_pk_bf16_f32 %0, %1, %2" : "=v"(r) : "v"(lo), "v"(hi));
    return r;
}
__device__ __forceinline__ f32x4 MFMA(bf16x8 a, bf16x8 b, f32x4 c) {
    return __builtin_amdgcn_mfma_f32_16x16x32_bf16(a, b, c, 0, 0, 0);
}

// ---------------- weight cast: dl_w/dr_w [O][C][3][3] -> fragment-linear
// layout [side][tap][ohalf][kk][n_][lane(64)][8] bf16 so dconv B-operands are
// direct coalesced global loads (1 KB per wave-load, L2-resident).
__global__ __launch_bounds__(256) void wcast_k(
    const float* __restrict__ dlw, const float* __restrict__ drw,
    unsigned short* __restrict__ wd)
{
    int i = blockIdx.x * 256 + threadIdx.x;
    if (i >= 2 * 9 * CC * CC) return;
    int e  = i & 7;
    int l  = (i >> 3) & 63;
    int n_ = (i >> 9) & 3;
    int kk = (i >> 11) & 3;
    int oh = (i >> 13) & 1;
    int rest = i >> 14;
    int tap = rest % 9;
    int side = rest / 9;
    int o = oh * 64 + n_ * 16 + (l & 15);
    int c = kk * 32 + (l >> 4) * 8 + e;
    const float* src = side ? drw : dlw;
    wd[i] = f2bf(src[((size_t)o * CC + c) * 9 + tap]);
}

// ---------------- fused LayerNorm + V-GEMM: reads x once.
// outputs: Nt [B,H,W,C] bf16, V^T [B,H,C,W] bf16
__global__ __launch_bounds__(256) void lnv_k(
    const float* __restrict__ xl, const float* __restrict__ xr,
    const float* __restrict__ nlw, const float* __restrict__ nlb,
    const float* __restrict__ nrw, const float* __restrict__ nrb,
    const float* __restrict__ wlp, const float* __restrict__ blp,
    const float* __restrict__ wrp, const float* __restrict__ brp,
    unsigned short* __restrict__ ntl, unsigned short* __restrict__ ntr,
    unsigned short* __restrict__ vlo, unsigned short* __restrict__ vro)
{
    const int side = blockIdx.y;
    const float* x  = side ? xr : xl;
    const float* nw = side ? nrw : nlw;
    const float* nb = side ? nrb : nlb;
    const float* wv = side ? wrp : wlp;
    const float* bv = side ? brp : blp;
    unsigned short* nt = side ? ntr : ntl;
    unsigned short* vo = side ? vro : vlo;
    const int bid = blockIdx.x;
    const int wt = bid & 7, h = (bid >> 3) % HH, b = bid / (8 * HH);
    const int w0 = wt * 64;
    const int t = threadIdx.x;

    __shared__ unsigned short sA[64][136];    // x^T tile [w][c] bf16
    __shared__ unsigned short sB[128][136];   // weight [o][c] bf16
    __shared__ float red[8][64];
    __shared__ float smu[64], srs[64];

    {
        const int w = t & 63, cg = t >> 6;
        const float* xp = x + (size_t)b * CHW + (size_t)h * WW + w0 + w;
        float s = 0.f, q = 0.f;
        for (int i = 0; i < 16; i++) {
            int c = cg * 32 + i * 2;
            float v0 = xp[(size_t)c * HW];
            float v1 = xp[(size_t)(c + 1) * HW];
            *(uint32_t*)&sA[w][c] = cvtpk(v0, v1);
            s += v0 + v1; q += v0 * v0 + v1 * v1;
        }
        red[cg][w] = s; red[4 + cg][w] = q;
    }
    for (int it = 0; it < 16; it++) {
        int f = it * 1024 + t * 4;
        int o = f >> 7, c = f & 127;
        float4 v = *(const float4*)(wv + o * CC + c);
        *(uint32_t*)&sB[o][c]     = cvtpk(v.x, v.y);
        *(uint32_t*)&sB[o][c + 2] = cvtpk(v.z, v.w);
    }
    __syncthreads();
    if (t < 64) {
        float S = red[0][t] + red[1][t] + red[2][t] + red[3][t];
        float Q = red[4][t] + red[5][t] + red[6][t] + red[7][t];
        float mu = S * (1.f / CC);
        float var = fmaxf(Q * (1.f / CC) - mu * mu, 0.f);
        smu[t] = mu; srs[t] = rsqrtf(var + 1e-6f);
    }
    __syncthreads();
    {   // LayerNorm output (from bf16 x in sA)
        const int w = t >> 2, c0 = (t & 3) * 32;
        const float mu = smu[w], rs = srs[w];
        unsigned short* np = nt + ((size_t)(b * HH + h) * WW + w0 + w) * CC;
        for (int i = 0; i < 32; i += 2) {
            int c = c0 + i;
            float v0 = (bf2f(sA[w][c]) - mu) * rs * nw[c] + nb[c];
            float v1 = (bf2f(sA[w][c + 1]) - mu) * rs * nw[c + 1] + nb[c + 1];
            *(uint32_t*)&np[c] = cvtpk(v0, v1);
        }
    }
    // V GEMM (reads only; no extra barrier needed)
    const int wid = t >> 6, l = t & 63, lr = l & 15, lg = l >> 4;
    f32x4 acc[8] = {};
    for (int kk = 0; kk < 4; kk++) {
        bf16x8 a = *(const bf16x8*)&sA[wid * 16 + lr][kk * 32 + lg * 8];
#pragma unroll
        for (int n_ = 0; n_ < 8; n_++) {
            bf16x8 bb = *(const bf16x8*)&sB[n_ * 16 + lr][kk * 32 + lg * 8];
            acc[n_] = MFMA(a, bb, acc[n_]);
        }
    }
    unsigned short* vp = vo + ((size_t)(b * HH + h) * CC) * WW + w0;
    for (int n_ = 0; n_ < 8; n_++) {
        int o = n_ * 16 + lr;
        float bias = bv[o];
        uint2 uu;
        uu.x = cvtpk(acc[n_][0] + bias, acc[n_][1] + bias);
        uu.y = cvtpk(acc[n_][2] + bias, acc[n_][3] + bias);
        *(uint2*)&vp[(size_t)o * WW + wid * 16 + lg * 4] = uu;
    }
}

// ---------------- K = dilated 3x3 conv (dilation 4, pad 4) over N -> [B,H,W,C] bf16
// 128-wide output tile; A via LDS, B direct global->reg (fragment-linear, L2-hot).
__global__ __launch_bounds__(256) void dconv_k(
    const unsigned short* __restrict__ ntl, const unsigned short* __restrict__ ntr,
    const unsigned short* __restrict__ wfr,
    const float* __restrict__ dlb, const float* __restrict__ drb,
    unsigned short* __restrict__ klo, unsigned short* __restrict__ kro)
{
    const int side = blockIdx.y;
    const unsigned short* nt = side ? ntr : ntl;
    const unsigned short* wbase = wfr + (size_t)side * 9 * 16384;
    const float* bd = side ? drb : dlb;
    unsigned short* ko = side ? kro : klo;
    // bijective XCD swizzle (1536 = 8*192): consecutive logical ids per XCD
    const int bid0 = blockIdx.x;
    const int lgc = (bid0 & 7) * 192 + (bid0 >> 3);
    const int wt = lgc & 3;
    const int hb = lgc >> 2;          // 0..383
    const int h = hb % HH, b = hb / HH;
    const int w0 = wt * 128;
    const int t = threadIdx.x;
    const int wid = t >> 6, l = t & 63, lr = l & 15, lg = l >> 4;
    const int whalf = wid & 1, ohalf = wid >> 1;

    __shared__ unsigned short sA[136][136];   // one dy-row of N, w0-4 .. w0+131

    f32x4 acc[4][4] = {};   // [g: w-subgroup][n: o-subgroup]
    for (int dy = 0; dy < 3; dy++) {
        const int hh = h + 4 * (dy - 1);
        const bool hok = (hh >= 0 && hh < HH);
        __syncthreads();
        for (int f = t * 8; f < 136 * 128; f += 2048) {
            int wloc = f >> 7, c = f & 127;
            int w = w0 - 4 + wloc;
            bf16x8 v = {0, 0, 0, 0, 0, 0, 0, 0};
            if (hok && w >= 0 && w < WW)
                v = *(const bf16x8*)(nt + ((size_t)(b * HH + hh) * WW + w) * CC + c);
            *(bf16x8*)&sA[wloc][c] = v;
        }
        __syncthreads();
#pragma unroll
        for (int dx = 0; dx < 3; dx++) {
            const unsigned short* wtap =
                wbase + (size_t)(dy * 3 + dx) * 16384 + ohalf * 8192 + l * 8;
#pragma unroll
            for (int kk = 0; kk < 4; kk++) {
                bf16x8 bfr[4];
#pragma unroll
                for (int n_ = 0; n_ < 4; n_++)
                    bfr[n_] = *(const bf16x8*)(wtap + (kk * 4 + n_) * 512);
                bf16x8 af[4];
#pragma unroll
                for (int g = 0; g < 4; g++)
                    af[g] = *(const bf16x8*)&sA[whalf * 64 + g * 16 + lr + 4 * dx][kk * 32 + lg * 8];
#pragma unroll
                for (int g = 0; g < 4; g++)
#pragma unroll
                    for (int n_ = 0; n_ < 4; n_++)
                        acc[g][n_] = MFMA(af[g], bfr[n_], acc[g][n_]);
            }
        }
    }
    unsigned short* kp = ko + ((size_t)(b * HH + h) * WW + w0) * CC;
    for (int g = 0; g < 4; g++)
        for (int n_ = 0; n_ < 4; n_++) {
            int o = ohalf * 64 + n_ * 16 + lr;
            float bias = bd[o];
            for (int j = 0; j < 4; j++) {
                int w = whalf * 64 + g * 16 + lg * 4 + j;
                kp[(size_t)w * CC + o] = f2bf(acc[g][n_][j] + bias);
            }
        }
}

// ---------------- fused Q-GEMM + flash attention (swapped-operand, QBLK=128)
// LDS 51 KB -> 3 blocks/CU via LDS limit alone; launch_bounds(256,2) so the
// register allocator is NOT capped (round-5 lesson: (256,3) -> 84 VGPR ->
// scratch spills -> 3x HBM traffic).
__global__ __launch_bounds__(256, 2) void attn_k(
    const unsigned short* __restrict__ ntl, const unsigned short* __restrict__ ntr,
    const unsigned short* __restrict__ kl,  const unsigned short* __restrict__ kr,
    const unsigned short* __restrict__ vtl, const unsigned short* __restrict__ vtr,
    const float* __restrict__ lp1w, const float* __restrict__ lp1b,
    const float* __restrict__ rp1w, const float* __restrict__ rp1b,
    const float* __restrict__ xl, const float* __restrict__ xr,
    const float* __restrict__ beta, const float* __restrict__ gamma,
    float* __restrict__ out)
{
    __shared__ __align__(16) char smem[52224];
    unsigned short* sQ  = (unsigned short*)smem;             // [128][136] phase A
    unsigned short* sWh = (unsigned short*)(smem + 34816);   // [64][136]  Wq half
    unsigned short* sKt = (unsigned short*)smem;             // [64][136]  phase B (alias)
    unsigned short* sVt = (unsigned short*)(smem + 17408);   // [128][72]  phase B (alias)

    const int dir = blockIdx.z;
    const unsigned short* nq  = dir ? ntr : ntl;
    const unsigned short* kws = dir ? kl : kr;
    const unsigned short* vws = dir ? vtl : vtr;
    const float* wq   = dir ? rp1w : lp1w;
    const float* bq   = dir ? rp1b : lp1b;
    const float* xres = dir ? xr : xl;
    const float* mult = dir ? gamma : beta;
    float* op = out + (size_t)dir * TENS;

    // XCD-locality swizzle: 4 q-blocks of one bh land consecutively on one XCD
    const int bid = blockIdx.x;
    const int xcd = bid & 7;
    const int s   = bid >> 3;         // 0..191
    const int qb  = s & 3;
    const int bh  = xcd + 8 * (s >> 2);   // 0..383
    const int q0  = qb * 128;
    const int t = threadIdx.x;
    const int wid = t >> 6, l = t & 63, lr = l & 15, lg = l >> 4;

    const unsigned short* ksrc = kws + (size_t)bh * WW * CC;          // [w][c]
    const unsigned short* vsrc = vws + (size_t)bh * CC * WW;          // [c][w]

    // ---- issue K/V tile-0 global loads early (T14) ----
    bf16x8 kreg[4], vreg[4];
#pragma unroll
    for (int it = 0; it < 4; it++) {
        int f = it * 2048 + t * 8;
        kreg[it] = *(const bf16x8*)(ksrc + f);
    }
#pragma unroll
    for (int it = 0; it < 4; it++) {
        int f = it * 2048 + t * 8;
        int c = f >> 6, k = f & 63;
        vreg[it] = *(const bf16x8*)(vsrc + (size_t)c * WW + k);
    }

    // ---- Phase A: stage N tile (128 q-rows); Wq in 2 halves of 64 rows ----
    {
        const unsigned short* nsrc = nq + ((size_t)bh * WW + q0) * CC;
        for (int it = 0; it < 8; it++) {
            int f = it * 2048 + t * 8;
            *(bf16x8*)&sQ[(f >> 7) * 136 + (f & 127)] = *(const bf16x8*)(nsrc + f);
        }
        for (int it = 0; it < 8; it++) {
            int f = it * 1024 + t * 4;
            int o = f >> 7, c = f & 127;
            float4 v = *(const float4*)(wq + o * CC + c);
            *(uint32_t*)&sWh[o * 136 + c]     = cvtpk(v.x, v.y);
            *(uint32_t*)&sWh[o * 136 + c + 2] = cvtpk(v.z, v.w);
        }
    }
    f32x4 qacc[2][8] = {};
    __syncthreads();
    for (int kk = 0; kk < 4; kk++) {
        bf16x8 a0 = *(const bf16x8*)&sQ[(wid * 32 + lr) * 136 + kk * 32 + lg * 8];
        bf16x8 a1 = *(const bf16x8*)&sQ[(wid * 32 + 16 + lr) * 136 + kk * 32 + lg * 8];
#pragma unroll
        for (int n_ = 0; n_ < 4; n_++) {
            bf16x8 b = *(const bf16x8*)&sWh[(n_ * 16 + lr) * 136 + kk * 32 + lg * 8];
            qacc[0][n_] = MFMA(a0, b, qacc[0][n_]);
            qacc[1][n_] = MFMA(a1, b, qacc[1][n_]);
        }
    }
    __syncthreads();
    for (int it = 0; it < 8; it++) {
        int f = it * 1024 + t * 4;
        int o = f >> 7, c = f & 127;
        float4 v = *(const float4*)(wq + (o + 64) * CC + c);
        *(uint32_t*)&sWh[o * 136 + c]     = cvtpk(v.x, v.y);
        *(uint32_t*)&sWh[o * 136 + c + 2] = cvtpk(v.z, v.w);
    }
    __syncthreads();
    for (int kk = 0; kk < 4; kk++) {
        bf16x8 a0 = *(const bf16x8*)&sQ[(wid * 32 + lr) * 136 + kk * 32 + lg * 8];
        bf16x8 a1 = *(const bf16x8*)&sQ[(wid * 32 + 16 + lr) * 136 + kk * 32 + lg * 8];
#pragma unroll
        for (int n_ = 0; n_ < 4; n_++) {
            bf16x8 b = *(const bf16x8*)&sWh[(n_ * 16 + lr) * 136 + kk * 32 + lg * 8];
            qacc[0][4 + n_] = MFMA(a0, b, qacc[0][4 + n_]);
            qacc[1][4 + n_] = MFMA(a1, b, qacc[1][4 + n_]);
        }
    }
    __syncthreads();   // all reads of sQ/sWh done before overwrite
    {
        const float SCL = 0.08838834764831845f * 1.4426950408889634f;  // C^-0.5 * log2e
#pragma unroll
        for (int mg = 0; mg < 2; mg++)
#pragma unroll
            for (int n_ = 0; n_ < 8; n_++) {
                float bias = bq[n_ * 16 + lr];
#pragma unroll
                for (int j = 0; j < 4; j++)
                    sQ[(wid * 32 + mg * 16 + lg * 4 + j) * 136 + n_ * 16 + lr] =
                        f2bf((qacc[mg][n_][j] + bias) * SCL);
            }
    }
    __syncthreads();
    bf16x8 qf[2][4];
#pragma unroll
    for (int qg = 0; qg < 2; qg++)
#pragma unroll
        for (int kk = 0; kk < 4; kk++)
            qf[qg][kk] = *(const bf16x8*)&sQ[(wid * 32 + qg * 16 + lr) * 136 + kk * 32 + lg * 8];

    // ---- Phase B: online-softmax attention, swapped operands ----
    // lane holds P[k=n*16+lg*4+j][q=wid*32+qg*16+lr] -> row-local softmax per qg
    f32x4 oacc[8][2] = {};           // O^T[c=n*16+lg*4+j][q per qg]
    float mrow[2] = {-1e30f, -1e30f};
    float lrow[2] = {0.f, 0.f};
    const int src0 = lr + ((l & 16) << 1);   // lr + 32*(lg&1)
    const int src1 = src0 + 16;
    const int hi = lg >> 1;

    for (int kb = 0; kb < 8; kb++) {
        __syncthreads();   // prior reads of sKt/sVt (or qf loads at kb=0) done
#pragma unroll
        for (int it = 0; it < 4; it++) {
            int f = it * 2048 + t * 8;
            *(bf16x8*)&sKt[(f >> 7) * 136 + (f & 127)] = kreg[it];
        }
#pragma unroll
        for (int it = 0; it < 4; it++) {
            int f = it * 2048 + t * 8;
            int c = f >> 6, k = f & 63;
            *(bf16x8*)&sVt[c * 72 + k] = vreg[it];
        }
        if (kb < 7) {
#pragma unroll
            for (int it = 0; it < 4; it++) {
                int f = it * 2048 + t * 8;
                kreg[it] = *(const bf16x8*)(ksrc + (kb + 1) * 64 * CC + f);
            }
#pragma unroll
            for (int it = 0; it < 4; it++) {
                int f = it * 2048 + t * 8;
                int c = f >> 6, k = f & 63;
                vreg[it] = *(const bf16x8*)(vsrc + (size_t)c * WW + (kb + 1) * 64 + k);
            }
        }
        __syncthreads();
        // QK^T swapped: A = K rows (k), B = Q (col=q); kf read once per (kk,n_)
        f32x4 sacc[2][4] = {};
        __builtin_amdgcn_s_setprio(1);
        for (int kk = 0; kk < 4; kk++)
#pragma unroll
            for (int n_ = 0; n_ < 4; n_++) {
                bf16x8 kf = *(const bf16x8*)&sKt[(n_ * 16 + lr) * 136 + kk * 32 + lg * 8];
                sacc[0][n_] = MFMA(kf, qf[0][kk], sacc[0][n_]);
                sacc[1][n_] = MFMA(kf, qf[1][kk], sacc[1][n_]);
            }
        __builtin_amdgcn_s_setprio(0);
        // tile max per qg
        float pm[2];
#pragma unroll
        for (int qg = 0; qg < 2; qg++) {
            float m_ = sacc[qg][0][0];
#pragma unroll
            for (int n_ = 0; n_ < 4; n_++)
#pragma unroll
                for (int j = 0; j < 4; j++) m_ = fmaxf(m_, sacc[qg][n_][j]);
            m_ = fmaxf(m_, __shfl_xor(m_, 16, 64));
            m_ = fmaxf(m_, __shfl_xor(m_, 32, 64));
            pm[qg] = m_;
        }
        // defer-max (T13): only rescale when max grew by > 8 (log2 units)
        bool need = (pm[0] - mrow[0] > 8.f) || (pm[1] - mrow[1] > 8.f);
        if (__any(need)) {
            float al[2];
#pragma unroll
            for (int qg = 0; qg < 2; qg++) {
                float mn = fmaxf(mrow[qg], pm[qg]);
                al[qg] = exp2f(mrow[qg] - mn);
                mrow[qg] = mn;
                lrow[qg] *= al[qg];
            }
#pragma unroll
            for (int n_ = 0; n_ < 8; n_++)
#pragma unroll
                for (int qg = 0; qg < 2; qg++) {
                    f32x4 o = oacc[n_][qg];
                    o[0] *= al[qg]; o[1] *= al[qg]; o[2] *= al[qg]; o[3] *= al[qg];
                    oacc[n_][qg] = o;
                }
        }
        // exponentials + row-sum (in place: sacc becomes P)
#pragma unroll
        for (int qg = 0; qg < 2; qg++) {
            float rs = 0.f;
#pragma unroll
            for (int n_ = 0; n_ < 4; n_++)
#pragma unroll
                for (int j = 0; j < 4; j++) {
                    float e = exp2f(sacc[qg][n_][j] - mrow[qg]);
                    sacc[qg][n_][j] = e;
                    rs += e;
                }
            rs += __shfl_xor(rs, 16, 64);
            rs += __shfl_xor(rs, 32, 64);
            lrow[qg] += rs;
        }
        // pack P to bf16 pairs: pk[qg][n][word]
        uint32_t pk[2][4][2];
#pragma unroll
        for (int qg = 0; qg < 2; qg++)
#pragma unroll
            for (int n_ = 0; n_ < 4; n_++) {
                pk[qg][n_][0] = cvtpk(sacc[qg][n_][0], sacc[qg][n_][1]);
                pk[qg][n_][1] = cvtpk(sacc[qg][n_][2], sacc[qg][n_][3]);
            }
        // PV swapped: A = V^T rows (c), B = P (col=q); va read once per (kk,n_)
#pragma unroll
        for (int kk = 0; kk < 2; kk++) {
            union { uint32_t u[4]; bf16x8 v; } pf[2];
#pragma unroll
            for (int qg = 0; qg < 2; qg++) {
                uint32_t q00 = __shfl(pk[qg][kk * 2][0],     src0, 64);
                uint32_t q01 = __shfl(pk[qg][kk * 2][1],     src0, 64);
                uint32_t q02 = __shfl(pk[qg][kk * 2][0],     src1, 64);
                uint32_t q03 = __shfl(pk[qg][kk * 2][1],     src1, 64);
                uint32_t q10 = __shfl(pk[qg][kk * 2 + 1][0], src0, 64);
                uint32_t q11 = __shfl(pk[qg][kk * 2 + 1][1], src0, 64);
                uint32_t q12 = __shfl(pk[qg][kk * 2 + 1][0], src1, 64);
                uint32_t q13 = __shfl(pk[qg][kk * 2 + 1][1], src1, 64);
                pf[qg].u[0] = hi ? q10 : q00;
                pf[qg].u[1] = hi ? q11 : q01;
                pf[qg].u[2] = hi ? q12 : q02;
                pf[qg].u[3] = hi ? q13 : q03;
            }
            __builtin_amdgcn_s_setprio(1);
#pragma unroll
            for (int n_ = 0; n_ < 8; n_++) {
                bf16x8 va = *(const bf16x8*)&sVt[(n_ * 16 + lr) * 72 + kk * 32 + lg * 8];
                oacc[n_][0] = MFMA(va, pf[0].v, oacc[n_][0]);
                oacc[n_][1] = MFMA(va, pf[1].v, oacc[n_][1]);
            }
            __builtin_amdgcn_s_setprio(0);
        }
    }

    // ---- epilogue: O^T layout is already [c][w] -> direct coalesced store ----
    const float inv0 = 1.f / lrow[0], inv1 = 1.f / lrow[1];
    const int b = bh / HH, h = bh % HH;
    const int w_0 = q0 + wid * 32 + lr;
    const float* xp0 = xres + (size_t)b * CHW + (size_t)h * WW + w_0;
    float* outp0 = op + (size_t)b * CHW + (size_t)h * WW + w_0;
#pragma unroll
    for (int n_ = 0; n_ < 8; n_++) {
        float4 m4 = *(const float4*)&mult[n_ * 16 + lg * 4];
#pragma unroll
        for (int j = 0; j < 4; j++) {
            int c = n_ * 16 + lg * 4 + j;
            float mj = (&m4.x)[j];
            outp0[(size_t)c * HW]      = xp0[(size_t)c * HW]      + oacc[n_][0][j] * inv0 * mj;
            outp0[(size_t)c * HW + 16] = xp0[(size_t)c * HW + 16] + oacc[n_][1][j] * inv1 * mj;
        }
    }
}

extern "C" void kernel_launch(void* const* d_in, const int* in_sizes, int n_in,
                              void* d_out, int out_size, void* d_ws, size_t ws_size,
                              hipStream_t stream)
{
    const float* xl   = (const float*)d_in[0];
    const float* xr   = (const float*)d_in[1];
    const float* nlw  = (const float*)d_in[2];
    const float* nlb  = (const float*)d_in[3];
    const float* nrw  = (const float*)d_in[4];
    const float* nrb  = (const float*)d_in[5];
    const float* lp1w = (const float*)d_in[6];
    const float* lp1b = (const float*)d_in[7];
    const float* rp1w = (const float*)d_in[8];
    const float* rp1b = (const float*)d_in[9];
    const float* dlw  = (const float*)d_in[10];
    const float* dlb  = (const float*)d_in[11];
    const float* drw  = (const float*)d_in[12];
    const float* drb  = (const float*)d_in[13];
    const float* lp2w = (const float*)d_in[14];
    const float* lp2b = (const float*)d_in[15];
    const float* rp2w = (const float*)d_in[16];
    const float* rp2b = (const float*)d_in[17];
    const float* beta = (const float*)d_in[18];
    const float* gamma= (const float*)d_in[19];
    float* out = (float*)d_out;

    unsigned short* ws = (unsigned short*)d_ws;
    const size_t A = (size_t)TENS;
    unsigned short* Ntl = ws;
    unsigned short* Ntr = ws + A;
    unsigned short* Kl  = ws + 2 * A;
    unsigned short* Kr  = ws + 3 * A;
    unsigned short* Vtl = ws + 4 * A;   // [B,H,C,W]
    unsigned short* Vtr = ws + 5 * A;
    unsigned short* Wd  = ws + 6 * A;   // fragment-linear dconv weights

    wcast_k<<<dim3(1152), 256, 0, stream>>>(dlw, drw, Wd);
    lnv_k<<<dim3(3072, 2), 256, 0, stream>>>(xl, xr, nlw, nlb, nrw, nrb,
        lp2w, lp2b, rp2w, rp2b, Ntl, Ntr, Vtl, Vtr);
    dconv_k<<<dim3(1536, 2), 256, 0, stream>>>(Ntl, Ntr, Wd, dlb, drb, Kl, Kr);
    attn_k<<<dim3(1536, 1, 2), 256, 0, stream>>>(Ntl, Ntr, Kl, Kr, Vtl, Vtr,
        lp1w, lp1b, rp1w, rp1b, xl, xr, beta, gamma, out);
}

// Round 7
// 505.661 us; speedup vs baseline: 1.4005x; 1.0738x over previous
//
#include <hip/hip_runtime.h>
#include <stdint.h>

#define CC 128
#define HH 192
#define WW 512
#define BB 2
#define HW (HH*WW)
#define CHW (CC*HW)
#define TENS (BB*CHW)   // 25165824 elems per [B,C,H,W] tensor

typedef __attribute__((ext_vector_type(8))) short bf16x8;
typedef __attribute__((ext_vector_type(4))) short bf16x4;
typedef __attribute__((ext_vector_type(4))) float f32x4;

__device__ __forceinline__ unsigned short f2bf(float f) {
    union { float f; unsigned u; } v; v.f = f;
    return (unsigned short)((v.u + 0x7FFFu + ((v.u >> 16) & 1u)) >> 16);
}
__device__ __forceinline__ float bf2f(unsigned short u) {
    union { unsigned u; float f; } v; v.u = ((unsigned)u) << 16;
    return v.f;
}
__device__ __forceinline__ uint32_t cvtpk(float lo, float hi) {
    uint32_t r;
    asm("v_cvt_pk_bf16_f32 %0, %1, %2" : "=v"(r) : "v"(lo), "v"(hi));
    return r;
}
__device__ __forceinline__ f32x4 MFMA(bf16x8 a, bf16x8 b, f32x4 c) {
    return __builtin_amdgcn_mfma_f32_16x16x32_bf16(a, b, c, 0, 0, 0);
}
__device__ __forceinline__ f32x4 MFMA16(bf16x4 a, bf16x4 b, f32x4 c) {
#if __has_builtin(__builtin_amdgcn_mfma_f32_16x16x16_bf16)
    return __builtin_amdgcn_mfma_f32_16x16x16_bf16(a, b, c, 0, 0, 0);
#elif __has_builtin(__builtin_amdgcn_mfma_f32_16x16x16bf16_1k)
    return __builtin_amdgcn_mfma_f32_16x16x16bf16_1k(a, b, c, 0, 0, 0);
#else
    f32x4 d = c;
    asm("v_mfma_f32_16x16x16_bf16 %0, %1, %2, %0" : "+v"(d) : "v"(a), "v"(b));
    return d;
#endif
}

// ---------------- weight cast: dl_w/dr_w [O][C][3][3] -> fragment-linear
// layout [side][tap][ohalf][kk][n_][lane(64)][8] bf16 so dconv B-operands are
// direct coalesced global loads (1 KB per wave-load, L2-resident).
__global__ __launch_bounds__(256) void wcast_k(
    const float* __restrict__ dlw, const float* __restrict__ drw,
    unsigned short* __restrict__ wd)
{
    int i = blockIdx.x * 256 + threadIdx.x;
    if (i >= 2 * 9 * CC * CC) return;
    int e  = i & 7;
    int l  = (i >> 3) & 63;
    int n_ = (i >> 9) & 3;
    int kk = (i >> 11) & 3;
    int oh = (i >> 13) & 1;
    int rest = i >> 14;
    int tap = rest % 9;
    int side = rest / 9;
    int o = oh * 64 + n_ * 16 + (l & 15);
    int c = kk * 32 + (l >> 4) * 8 + e;
    const float* src = side ? drw : dlw;
    wd[i] = f2bf(src[((size_t)o * CC + c) * 9 + tap]);
}

// ---------------- fused LayerNorm + V-GEMM: reads x once.
// outputs: Nt [B,H,W,C] bf16, V^T [B,H,C,W] bf16
__global__ __launch_bounds__(256) void lnv_k(
    const float* __restrict__ xl, const float* __restrict__ xr,
    const float* __restrict__ nlw, const float* __restrict__ nlb,
    const float* __restrict__ nrw, const float* __restrict__ nrb,
    const float* __restrict__ wlp, const float* __restrict__ blp,
    const float* __restrict__ wrp, const float* __restrict__ brp,
    unsigned short* __restrict__ ntl, unsigned short* __restrict__ ntr,
    unsigned short* __restrict__ vlo, unsigned short* __restrict__ vro)
{
    const int side = blockIdx.y;
    const float* x  = side ? xr : xl;
    const float* nw = side ? nrw : nlw;
    const float* nb = side ? nrb : nlb;
    const float* wv = side ? wrp : wlp;
    const float* bv = side ? brp : blp;
    unsigned short* nt = side ? ntr : ntl;
    unsigned short* vo = side ? vro : vlo;
    const int bid = blockIdx.x;
    const int wt = bid & 7, h = (bid >> 3) % HH, b = bid / (8 * HH);
    const int w0 = wt * 64;
    const int t = threadIdx.x;

    __shared__ unsigned short sA[64][136];    // x^T tile [w][c] bf16
    __shared__ unsigned short sB[128][136];   // weight [o][c] bf16
    __shared__ float red[8][64];
    __shared__ float smu[64], srs[64];

    {
        const int w = t & 63, cg = t >> 6;
        const float* xp = x + (size_t)b * CHW + (size_t)h * WW + w0 + w;
        float s = 0.f, q = 0.f;
        for (int i = 0; i < 16; i++) {
            int c = cg * 32 + i * 2;
            float v0 = xp[(size_t)c * HW];
            float v1 = xp[(size_t)(c + 1) * HW];
            *(uint32_t*)&sA[w][c] = cvtpk(v0, v1);
            s += v0 + v1; q += v0 * v0 + v1 * v1;
        }
        red[cg][w] = s; red[4 + cg][w] = q;
    }
    for (int it = 0; it < 16; it++) {
        int f = it * 1024 + t * 4;
        int o = f >> 7, c = f & 127;
        float4 v = *(const float4*)(wv + o * CC + c);
        *(uint32_t*)&sB[o][c]     = cvtpk(v.x, v.y);
        *(uint32_t*)&sB[o][c + 2] = cvtpk(v.z, v.w);
    }
    __syncthreads();
    if (t < 64) {
        float S = red[0][t] + red[1][t] + red[2][t] + red[3][t];
        float Q = red[4][t] + red[5][t] + red[6][t] + red[7][t];
        float mu = S * (1.f / CC);
        float var = fmaxf(Q * (1.f / CC) - mu * mu, 0.f);
        smu[t] = mu; srs[t] = rsqrtf(var + 1e-6f);
    }
    __syncthreads();
    {   // LayerNorm output, coalesced: 64 lanes write one contiguous 256B row
        const int cl = (t & 63) * 2, wg = t >> 6;
        const float nwa = nw[cl], nwb = nw[cl + 1];
        const float nba = nb[cl], nbb = nb[cl + 1];
        unsigned short* npb = nt + ((size_t)(b * HH + h) * WW + w0) * CC;
        for (int wp = 0; wp < 16; wp++) {
            int w = wp * 4 + wg;
            float mu = smu[w], rs = srs[w];
            float v0 = (bf2f(sA[w][cl]) - mu) * rs * nwa + nba;
            float v1 = (bf2f(sA[w][cl + 1]) - mu) * rs * nwb + nbb;
            *(uint32_t*)&npb[(size_t)w * CC + cl] = cvtpk(v0, v1);
        }
    }
    // V GEMM (reads only; no extra barrier needed)
    const int wid = t >> 6, l = t & 63, lr = l & 15, lg = l >> 4;
    f32x4 acc[8] = {};
    for (int kk = 0; kk < 4; kk++) {
        bf16x8 a = *(const bf16x8*)&sA[wid * 16 + lr][kk * 32 + lg * 8];
#pragma unroll
        for (int n_ = 0; n_ < 8; n_++) {
            bf16x8 bb = *(const bf16x8*)&sB[n_ * 16 + lr][kk * 32 + lg * 8];
            acc[n_] = MFMA(a, bb, acc[n_]);
        }
    }
    unsigned short* vp = vo + ((size_t)(b * HH + h) * CC) * WW + w0;
    for (int n_ = 0; n_ < 8; n_++) {
        int o = n_ * 16 + lr;
        float bias = bv[o];
        uint2 uu;
        uu.x = cvtpk(acc[n_][0] + bias, acc[n_][1] + bias);
        uu.y = cvtpk(acc[n_][2] + bias, acc[n_][3] + bias);
        *(uint2*)&vp[(size_t)o * WW + wid * 16 + lg * 4] = uu;
    }
}

// ---------------- K = dilated 3x3 conv (dilation 4, pad 4) over N -> [B,H,W,C] bf16
// 128-wide output tile; A via LDS, B direct global->reg (fragment-linear, L2-hot).
__global__ __launch_bounds__(256) void dconv_k(
    const unsigned short* __restrict__ ntl, const unsigned short* __restrict__ ntr,
    const unsigned short* __restrict__ wfr,
    const float* __restrict__ dlb, const float* __restrict__ drb,
    unsigned short* __restrict__ klo, unsigned short* __restrict__ kro)
{
    const int side = blockIdx.y;
    const unsigned short* nt = side ? ntr : ntl;
    const unsigned short* wbase = wfr + (size_t)side * 9 * 16384;
    const float* bd = side ? drb : dlb;
    unsigned short* ko = side ? kro : klo;
    // bijective XCD swizzle (1536 = 8*192): consecutive logical ids per XCD
    const int bid0 = blockIdx.x;
    const int lgc = (bid0 & 7) * 192 + (bid0 >> 3);
    const int wt = lgc & 3;
    const int hb = lgc >> 2;          // 0..383
    const int h = hb % HH, b = hb / HH;
    const int w0 = wt * 128;
    const int t = threadIdx.x;
    const int wid = t >> 6, l = t & 63, lr = l & 15, lg = l >> 4;
    const int whalf = wid & 1, ohalf = wid >> 1;

    __shared__ unsigned short sA[136][136];   // one dy-row of N, w0-4 .. w0+131

    f32x4 acc[4][4] = {};   // [g: w-subgroup][n: o-subgroup]
    for (int dy = 0; dy < 3; dy++) {
        const int hh = h + 4 * (dy - 1);
        const bool hok = (hh >= 0 && hh < HH);
        __syncthreads();
        for (int f = t * 8; f < 136 * 128; f += 2048) {
            int wloc = f >> 7, c = f & 127;
            int w = w0 - 4 + wloc;
            bf16x8 v = {0, 0, 0, 0, 0, 0, 0, 0};
            if (hok && w >= 0 && w < WW)
                v = *(const bf16x8*)(nt + ((size_t)(b * HH + hh) * WW + w) * CC + c);
            *(bf16x8*)&sA[wloc][c] = v;
        }
        __syncthreads();
#pragma unroll
        for (int dx = 0; dx < 3; dx++) {
            const unsigned short* wtap =
                wbase + (size_t)(dy * 3 + dx) * 16384 + ohalf * 8192 + l * 8;
#pragma unroll
            for (int kk = 0; kk < 4; kk++) {
                bf16x8 bfr[4];
#pragma unroll
                for (int n_ = 0; n_ < 4; n_++)
                    bfr[n_] = *(const bf16x8*)(wtap + (kk * 4 + n_) * 512);
                bf16x8 af[4];
#pragma unroll
                for (int g = 0; g < 4; g++)
                    af[g] = *(const bf16x8*)&sA[whalf * 64 + g * 16 + lr + 4 * dx][kk * 32 + lg * 8];
#pragma unroll
                for (int g = 0; g < 4; g++)
#pragma unroll
                    for (int n_ = 0; n_ < 4; n_++)
                        acc[g][n_] = MFMA(af[g], bfr[n_], acc[g][n_]);
            }
        }
    }
    unsigned short* kp = ko + ((size_t)(b * HH + h) * WW + w0) * CC;
    for (int g = 0; g < 4; g++)
        for (int n_ = 0; n_ < 4; n_++) {
            int o = ohalf * 64 + n_ * 16 + lr;
            float bias = bd[o];
            for (int j = 0; j < 4; j++) {
                int w = whalf * 64 + g * 16 + lg * 4 + j;
                kp[(size_t)w * CC + o] = f2bf(acc[g][n_][j] + bias);
            }
        }
}

// ---------------- fused Q-GEMM + flash attention (swapped-operand, QBLK=128)
// PV uses 16x16x16 MFMA: P's QK^T output layout IS the K=16 B-fragment layout,
// so no cross-lane shuffle is needed (deletes 16 bpermute + 8 selects / tile).
__global__ __launch_bounds__(256, 2) void attn_k(
    const unsigned short* __restrict__ ntl, const unsigned short* __restrict__ ntr,
    const unsigned short* __restrict__ kl,  const unsigned short* __restrict__ kr,
    const unsigned short* __restrict__ vtl, const unsigned short* __restrict__ vtr,
    const float* __restrict__ lp1w, const float* __restrict__ lp1b,
    const float* __restrict__ rp1w, const float* __restrict__ rp1b,
    const float* __restrict__ xl, const float* __restrict__ xr,
    const float* __restrict__ beta, const float* __restrict__ gamma,
    float* __restrict__ out)
{
    __shared__ __align__(16) char smem[52224];
    unsigned short* sQ  = (unsigned short*)smem;             // [128][136] phase A
    unsigned short* sWh = (unsigned short*)(smem + 34816);   // [64][136]  Wq half
    unsigned short* sKt = (unsigned short*)smem;             // [64][136]  phase B (alias)
    unsigned short* sVt = (unsigned short*)(smem + 17408);   // [128][72]  phase B (alias)

    const int dir = blockIdx.z;
    const unsigned short* nq  = dir ? ntr : ntl;
    const unsigned short* kws = dir ? kl : kr;
    const unsigned short* vws = dir ? vtl : vtr;
    const float* wq   = dir ? rp1w : lp1w;
    const float* bq   = dir ? rp1b : lp1b;
    const float* xres = dir ? xr : xl;
    const float* mult = dir ? gamma : beta;
    float* op = out + (size_t)dir * TENS;

    // XCD-locality swizzle: 4 q-blocks of one bh land consecutively on one XCD
    const int bid = blockIdx.x;
    const int xcd = bid & 7;
    const int s   = bid >> 3;         // 0..191
    const int qb  = s & 3;
    const int bh  = xcd + 8 * (s >> 2);   // 0..383
    const int q0  = qb * 128;
    const int t = threadIdx.x;
    const int wid = t >> 6, l = t & 63, lr = l & 15, lg = l >> 4;

    const unsigned short* ksrc = kws + (size_t)bh * WW * CC;          // [w][c]
    const unsigned short* vsrc = vws + (size_t)bh * CC * WW;          // [c][w]

    // ---- issue K/V tile-0 global loads early (T14) ----
    bf16x8 kreg[4], vreg[4];
#pragma unroll
    for (int it = 0; it < 4; it++) {
        int f = it * 2048 + t * 8;
        kreg[it] = *(const bf16x8*)(ksrc + f);
    }
#pragma unroll
    for (int it = 0; it < 4; it++) {
        int f = it * 2048 + t * 8;
        int c = f >> 6, k = f & 63;
        vreg[it] = *(const bf16x8*)(vsrc + (size_t)c * WW + k);
    }

    // ---- Phase A: stage N tile (128 q-rows); Wq in 2 halves of 64 rows ----
    {
        const unsigned short* nsrc = nq + ((size_t)bh * WW + q0) * CC;
        for (int it = 0; it < 8; it++) {
            int f = it * 2048 + t * 8;
            *(bf16x8*)&sQ[(f >> 7) * 136 + (f & 127)] = *(const bf16x8*)(nsrc + f);
        }
        for (int it = 0; it < 8; it++) {
            int f = it * 1024 + t * 4;
            int o = f >> 7, c = f & 127;
            float4 v = *(const float4*)(wq + o * CC + c);
            *(uint32_t*)&sWh[o * 136 + c]     = cvtpk(v.x, v.y);
            *(uint32_t*)&sWh[o * 136 + c + 2] = cvtpk(v.z, v.w);
        }
    }
    f32x4 qacc[2][8] = {};
    __syncthreads();
    for (int kk = 0; kk < 4; kk++) {
        bf16x8 a0 = *(const bf16x8*)&sQ[(wid * 32 + lr) * 136 + kk * 32 + lg * 8];
        bf16x8 a1 = *(const bf16x8*)&sQ[(wid * 32 + 16 + lr) * 136 + kk * 32 + lg * 8];
#pragma unroll
        for (int n_ = 0; n_ < 4; n_++) {
            bf16x8 b = *(const bf16x8*)&sWh[(n_ * 16 + lr) * 136 + kk * 32 + lg * 8];
            qacc[0][n_] = MFMA(a0, b, qacc[0][n_]);
            qacc[1][n_] = MFMA(a1, b, qacc[1][n_]);
        }
    }
    __syncthreads();
    for (int it = 0; it < 8; it++) {
        int f = it * 1024 + t * 4;
        int o = f >> 7, c = f & 127;
        float4 v = *(const float4*)(wq + (o + 64) * CC + c);
        *(uint32_t*)&sWh[o * 136 + c]     = cvtpk(v.x, v.y);
        *(uint32_t*)&sWh[o * 136 + c + 2] = cvtpk(v.z, v.w);
    }
    __syncthreads();
    for (int kk = 0; kk < 4; kk++) {
        bf16x8 a0 = *(const bf16x8*)&sQ[(wid * 32 + lr) * 136 + kk * 32 + lg * 8];
        bf16x8 a1 = *(const bf16x8*)&sQ[(wid * 32 + 16 + lr) * 136 + kk * 32 + lg * 8];
#pragma unroll
        for (int n_ = 0; n_ < 4; n_++) {
            bf16x8 b = *(const bf16x8*)&sWh[(n_ * 16 + lr) * 136 + kk * 32 + lg * 8];
            qacc[0][4 + n_] = MFMA(a0, b, qacc[0][4 + n_]);
            qacc[1][4 + n_] = MFMA(a1, b, qacc[1][4 + n_]);
        }
    }
    __syncthreads();   // all reads of sQ/sWh done before overwrite
    {
        const float SCL = 0.08838834764831845f * 1.4426950408889634f;  // C^-0.5 * log2e
#pragma unroll
        for (int mg = 0; mg < 2; mg++)
#pragma unroll
            for (int n_ = 0; n_ < 8; n_++) {
                float bias = bq[n_ * 16 + lr];
#pragma unroll
                for (int j = 0; j < 4; j++)
                    sQ[(wid * 32 + mg * 16 + lg * 4 + j) * 136 + n_ * 16 + lr] =
                        f2bf((qacc[mg][n_][j] + bias) * SCL);
            }
    }
    __syncthreads();
    bf16x8 qf[2][4];
#pragma unroll
    for (int qg = 0; qg < 2; qg++)
#pragma unroll
        for (int kk = 0; kk < 4; kk++)
            qf[qg][kk] = *(const bf16x8*)&sQ[(wid * 32 + qg * 16 + lr) * 136 + kk * 32 + lg * 8];

    // ---- Phase B: online-softmax attention, swapped operands ----
    // lane holds P[k=n*16+lg*4+j][q=wid*32+qg*16+lr] -> row-local softmax per qg
    f32x4 oacc[8][2] = {};           // O^T[c=n*16+lg*4+j][q per qg]
    float mrow[2] = {-1e30f, -1e30f};
    float lrow[2] = {0.f, 0.f};

    for (int kb = 0; kb < 8; kb++) {
        __syncthreads();   // prior reads of sKt/sVt (or qf loads at kb=0) done
#pragma unroll
        for (int it = 0; it < 4; it++) {
            int f = it * 2048 + t * 8;
            *(bf16x8*)&sKt[(f >> 7) * 136 + (f & 127)] = kreg[it];
        }
#pragma unroll
        for (int it = 0; it < 4; it++) {
            int f = it * 2048 + t * 8;
            int c = f >> 6, k = f & 63;
            *(bf16x8*)&sVt[c * 72 + k] = vreg[it];
        }
        if (kb < 7) {
#pragma unroll
            for (int it = 0; it < 4; it++) {
                int f = it * 2048 + t * 8;
                kreg[it] = *(const bf16x8*)(ksrc + (kb + 1) * 64 * CC + f);
            }
#pragma unroll
            for (int it = 0; it < 4; it++) {
                int f = it * 2048 + t * 8;
                int c = f >> 6, k = f & 63;
                vreg[it] = *(const bf16x8*)(vsrc + (size_t)c * WW + (kb + 1) * 64 + k);
            }
        }
        __syncthreads();
        // QK^T swapped: A = K rows (k), B = Q (col=q); kf read once per (kk,n_)
        f32x4 sacc[2][4] = {};
        __builtin_amdgcn_s_setprio(1);
        for (int kk = 0; kk < 4; kk++)
#pragma unroll
            for (int n_ = 0; n_ < 4; n_++) {
                bf16x8 kf = *(const bf16x8*)&sKt[(n_ * 16 + lr) * 136 + kk * 32 + lg * 8];
                sacc[0][n_] = MFMA(kf, qf[0][kk], sacc[0][n_]);
                sacc[1][n_] = MFMA(kf, qf[1][kk], sacc[1][n_]);
            }
        __builtin_amdgcn_s_setprio(0);
        // tile max per qg
        float pm[2];
#pragma unroll
        for (int qg = 0; qg < 2; qg++) {
            float m_ = sacc[qg][0][0];
#pragma unroll
            for (int n_ = 0; n_ < 4; n_++)
#pragma unroll
                for (int j = 0; j < 4; j++) m_ = fmaxf(m_, sacc[qg][n_][j]);
            m_ = fmaxf(m_, __shfl_xor(m_, 16, 64));
            m_ = fmaxf(m_, __shfl_xor(m_, 32, 64));
            pm[qg] = m_;
        }
        // defer-max (T13): only rescale when max grew by > 8 (log2 units)
        bool need = (pm[0] - mrow[0] > 8.f) || (pm[1] - mrow[1] > 8.f);
        if (__any(need)) {
            float al[2];
#pragma unroll
            for (int qg = 0; qg < 2; qg++) {
                float mn = fmaxf(mrow[qg], pm[qg]);
                al[qg] = exp2f(mrow[qg] - mn);
                mrow[qg] = mn;
                lrow[qg] *= al[qg];
            }
#pragma unroll
            for (int n_ = 0; n_ < 8; n_++)
#pragma unroll
                for (int qg = 0; qg < 2; qg++) {
                    f32x4 o = oacc[n_][qg];
                    o[0] *= al[qg]; o[1] *= al[qg]; o[2] *= al[qg]; o[3] *= al[qg];
                    oacc[n_][qg] = o;
                }
        }
        // exponentials + row-sum (in place: sacc becomes P)
#pragma unroll
        for (int qg = 0; qg < 2; qg++) {
            float rs = 0.f;
#pragma unroll
            for (int n_ = 0; n_ < 4; n_++)
#pragma unroll
                for (int j = 0; j < 4; j++) {
                    float e = exp2f(sacc[qg][n_][j] - mrow[qg]);
                    sacc[qg][n_][j] = e;
                    rs += e;
                }
            rs += __shfl_xor(rs, 16, 64);
            rs += __shfl_xor(rs, 32, 64);
            lrow[qg] += rs;
        }
        // PV via 16x16x16 MFMA: lane-local P fragment (k = n_*16 + lg*4 + j,
        // col = q = lr) IS the K=16 B-frag layout -> just cvtpk, no shuffle.
        __builtin_amdgcn_s_setprio(1);
#pragma unroll
        for (int n_ = 0; n_ < 4; n_++) {
            union { uint32_t u[2]; bf16x4 v; } b0, b1;
            b0.u[0] = cvtpk(sacc[0][n_][0], sacc[0][n_][1]);
            b0.u[1] = cvtpk(sacc[0][n_][2], sacc[0][n_][3]);
            b1.u[0] = cvtpk(sacc[1][n_][0], sacc[1][n_][1]);
            b1.u[1] = cvtpk(sacc[1][n_][2], sacc[1][n_][3]);
#pragma unroll
            for (int n8 = 0; n8 < 8; n8++) {
                bf16x4 va = *(const bf16x4*)&sVt[(n8 * 16 + lr) * 72 + n_ * 16 + lg * 4];
                oacc[n8][0] = MFMA16(va, b0.v, oacc[n8][0]);
                oacc[n8][1] = MFMA16(va, b1.v, oacc[n8][1]);
            }
        }
        __builtin_amdgcn_s_setprio(0);
    }

    // ---- epilogue: O^T layout is already [c][w] -> direct coalesced store ----
    const float inv0 = 1.f / lrow[0], inv1 = 1.f / lrow[1];
    const int b = bh / HH, h = bh % HH;
    const int w_0 = q0 + wid * 32 + lr;
    const float* xp0 = xres + (size_t)b * CHW + (size_t)h * WW + w_0;
    float* outp0 = op + (size_t)b * CHW + (size_t)h * WW + w_0;
#pragma unroll
    for (int n_ = 0; n_ < 8; n_++) {
        float4 m4 = *(const float4*)&mult[n_ * 16 + lg * 4];
#pragma unroll
        for (int j = 0; j < 4; j++) {
            int c = n_ * 16 + lg * 4 + j;
            float mj = (&m4.x)[j];
            outp0[(size_t)c * HW]      = xp0[(size_t)c * HW]      + oacc[n_][0][j] * inv0 * mj;
            outp0[(size_t)c * HW + 16] = xp0[(size_t)c * HW + 16] + oacc[n_][1][j] * inv1 * mj;
        }
    }
}

extern "C" void kernel_launch(void* const* d_in, const int* in_sizes, int n_in,
                              void* d_out, int out_size, void* d_ws, size_t ws_size,
                              hipStream_t stream)
{
    const float* xl   = (const float*)d_in[0];
    const float* xr   = (const float*)d_in[1];
    const float* nlw  = (const float*)d_in[2];
    const float* nlb  = (const float*)d_in[3];
    const float* nrw  = (const float*)d_in[4];
    const float* nrb  = (const float*)d_in[5];
    const float* lp1w = (const float*)d_in[6];
    const float* lp1b = (const float*)d_in[7];
    const float* rp1w = (const float*)d_in[8];
    const float* rp1b = (const float*)d_in[9];
    const float* dlw  = (const float*)d_in[10];
    const float* dlb  = (const float*)d_in[11];
    const float* drw  = (const float*)d_in[12];
    const float* drb  = (const float*)d_in[13];
    const float* lp2w = (const float*)d_in[14];
    const float* lp2b = (const float*)d_in[15];
    const float* rp2w = (const float*)d_in[16];
    const float* rp2b = (const float*)d_in[17];
    const float* beta = (const float*)d_in[18];
    const float* gamma= (const float*)d_in[19];
    float* out = (float*)d_out;

    unsigned short* ws = (unsigned short*)d_ws;
    const size_t A = (size_t)TENS;
    unsigned short* Ntl = ws;
    unsigned short* Ntr = ws + A;
    unsigned short* Kl  = ws + 2 * A;
    unsigned short* Kr  = ws + 3 * A;
    unsigned short* Vtl = ws + 4 * A;   // [B,H,C,W]
    unsigned short* Vtr = ws + 5 * A;
    unsigned short* Wd  = ws + 6 * A;   // fragment-linear dconv weights

    wcast_k<<<dim3(1152), 256, 0, stream>>>(dlw, drw, Wd);
    lnv_k<<<dim3(3072, 2), 256, 0, stream>>>(xl, xr, nlw, nlb, nrw, nrb,
        lp2w, lp2b, rp2w, rp2b, Ntl, Ntr, Vtl, Vtr);
    dconv_k<<<dim3(1536, 2), 256, 0, stream>>>(Ntl, Ntr, Wd, dlb, drb, Kl, Kr);
    attn_k<<<dim3(1536, 1, 2), 256, 0, stream>>>(Ntl, Ntr, Kl, Kr, Vtl, Vtr,
        lp1w, lp1b, rp1w, rp1b, xl, xr, beta, gamma, out);
}

// Round 8
// 505.165 us; speedup vs baseline: 1.4019x; 1.0010x over previous
//
#include <hip/hip_runtime.h>
#include <stdint.h>

#define CC 128
#define HH 192
#define WW 512
#define BB 2
#define HW (HH*WW)
#define CHW (CC*HW)
#define TENS (BB*CHW)   // 25165824 elems per [B,C,H,W] tensor

typedef __attribute__((ext_vector_type(8))) short bf16x8;
typedef __attribute__((ext_vector_type(4))) short bf16x4;
typedef __attribute__((ext_vector_type(4))) float f32x4;

__device__ __forceinline__ unsigned short f2bf(float f) {
    union { float f; unsigned u; } v; v.f = f;
    return (unsigned short)((v.u + 0x7FFFu + ((v.u >> 16) & 1u)) >> 16);
}
__device__ __forceinline__ float bf2f(unsigned short u) {
    union { unsigned u; float f; } v; v.u = ((unsigned)u) << 16;
    return v.f;
}
__device__ __forceinline__ uint32_t cvtpk(float lo, float hi) {
    uint32_t r;
    asm("v_cvt_pk_bf16_f32 %0, %1, %2" : "=v"(r) : "v"(lo), "v"(hi));
    return r;
}
__device__ __forceinline__ f32x4 MFMA(bf16x8 a, bf16x8 b, f32x4 c) {
    return __builtin_amdgcn_mfma_f32_16x16x32_bf16(a, b, c, 0, 0, 0);
}
__device__ __forceinline__ f32x4 MFMA16(bf16x4 a, bf16x4 b, f32x4 c) {
#if __has_builtin(__builtin_amdgcn_mfma_f32_16x16x16_bf16)
    return __builtin_amdgcn_mfma_f32_16x16x16_bf16(a, b, c, 0, 0, 0);
#elif __has_builtin(__builtin_amdgcn_mfma_f32_16x16x16bf16_1k)
    return __builtin_amdgcn_mfma_f32_16x16x16bf16_1k(a, b, c, 0, 0, 0);
#else
    f32x4 d = c;
    asm("v_mfma_f32_16x16x16_bf16 %0, %1, %2, %0" : "+v"(d) : "v"(a), "v"(b));
    return d;
#endif
}

// ---------------- weight cast: dl_w/dr_w [O][C][3][3] -> fragment-linear
// layout [side][tap][ohalf][kk][n_][lane(64)][8] bf16 so dconv B-operands are
// direct coalesced global loads (1 KB per wave-load, L2-resident).
__global__ __launch_bounds__(256) void wcast_k(
    const float* __restrict__ dlw, const float* __restrict__ drw,
    unsigned short* __restrict__ wd)
{
    int i = blockIdx.x * 256 + threadIdx.x;
    if (i >= 2 * 9 * CC * CC) return;
    int e  = i & 7;
    int l  = (i >> 3) & 63;
    int n_ = (i >> 9) & 3;
    int kk = (i >> 11) & 3;
    int oh = (i >> 13) & 1;
    int rest = i >> 14;
    int tap = rest % 9;
    int side = rest / 9;
    int o = oh * 64 + n_ * 16 + (l & 15);
    int c = kk * 32 + (l >> 4) * 8 + e;
    const float* src = side ? drw : dlw;
    wd[i] = f2bf(src[((size_t)o * CC + c) * 9 + tap]);
}

// ---------------- fused LayerNorm + V-GEMM: reads x once.
// outputs: Nt [B,H,W,C] bf16, V^T [B,H,C,W] bf16
__global__ __launch_bounds__(256) void lnv_k(
    const float* __restrict__ xl, const float* __restrict__ xr,
    const float* __restrict__ nlw, const float* __restrict__ nlb,
    const float* __restrict__ nrw, const float* __restrict__ nrb,
    const float* __restrict__ wlp, const float* __restrict__ blp,
    const float* __restrict__ wrp, const float* __restrict__ brp,
    unsigned short* __restrict__ ntl, unsigned short* __restrict__ ntr,
    unsigned short* __restrict__ vlo, unsigned short* __restrict__ vro)
{
    const int side = blockIdx.y;
    const float* x  = side ? xr : xl;
    const float* nw = side ? nrw : nlw;
    const float* nb = side ? nrb : nlb;
    const float* wv = side ? wrp : wlp;
    const float* bv = side ? brp : blp;
    unsigned short* nt = side ? ntr : ntl;
    unsigned short* vo = side ? vro : vlo;
    const int bid = blockIdx.x;
    const int wt = bid & 7, h = (bid >> 3) % HH, b = bid / (8 * HH);
    const int w0 = wt * 64;
    const int t = threadIdx.x;

    __shared__ unsigned short sA[64][136];    // x^T tile [w][c] bf16
    __shared__ unsigned short sB[128][136];   // weight [o][c] bf16
    __shared__ float red[8][64];
    __shared__ float smu[64], srs[64];

    {
        const int w = t & 63, cg = t >> 6;
        const float* xp = x + (size_t)b * CHW + (size_t)h * WW + w0 + w;
        float s = 0.f, q = 0.f;
        for (int i = 0; i < 16; i++) {
            int c = cg * 32 + i * 2;
            float v0 = xp[(size_t)c * HW];
            float v1 = xp[(size_t)(c + 1) * HW];
            *(uint32_t*)&sA[w][c] = cvtpk(v0, v1);
            s += v0 + v1; q += v0 * v0 + v1 * v1;
        }
        red[cg][w] = s; red[4 + cg][w] = q;
    }
    for (int it = 0; it < 16; it++) {
        int f = it * 1024 + t * 4;
        int o = f >> 7, c = f & 127;
        float4 v = *(const float4*)(wv + o * CC + c);
        *(uint32_t*)&sB[o][c]     = cvtpk(v.x, v.y);
        *(uint32_t*)&sB[o][c + 2] = cvtpk(v.z, v.w);
    }
    __syncthreads();
    if (t < 64) {
        float S = red[0][t] + red[1][t] + red[2][t] + red[3][t];
        float Q = red[4][t] + red[5][t] + red[6][t] + red[7][t];
        float mu = S * (1.f / CC);
        float var = fmaxf(Q * (1.f / CC) - mu * mu, 0.f);
        smu[t] = mu; srs[t] = rsqrtf(var + 1e-6f);
    }
    __syncthreads();
    {   // LayerNorm output, coalesced: 64 lanes write one contiguous 256B row
        const int cl = (t & 63) * 2, wg = t >> 6;
        const float nwa = nw[cl], nwb = nw[cl + 1];
        const float nba = nb[cl], nbb = nb[cl + 1];
        unsigned short* npb = nt + ((size_t)(b * HH + h) * WW + w0) * CC;
        for (int wp = 0; wp < 16; wp++) {
            int w = wp * 4 + wg;
            float mu = smu[w], rs = srs[w];
            float v0 = (bf2f(sA[w][cl]) - mu) * rs * nwa + nba;
            float v1 = (bf2f(sA[w][cl + 1]) - mu) * rs * nwb + nbb;
            *(uint32_t*)&npb[(size_t)w * CC + cl] = cvtpk(v0, v1);
        }
    }
    // V GEMM (reads only; no extra barrier needed)
    const int wid = t >> 6, l = t & 63, lr = l & 15, lg = l >> 4;
    f32x4 acc[8] = {};
    for (int kk = 0; kk < 4; kk++) {
        bf16x8 a = *(const bf16x8*)&sA[wid * 16 + lr][kk * 32 + lg * 8];
#pragma unroll
        for (int n_ = 0; n_ < 8; n_++) {
            bf16x8 bb = *(const bf16x8*)&sB[n_ * 16 + lr][kk * 32 + lg * 8];
            acc[n_] = MFMA(a, bb, acc[n_]);
        }
    }
    unsigned short* vp = vo + ((size_t)(b * HH + h) * CC) * WW + w0;
    for (int n_ = 0; n_ < 8; n_++) {
        int o = n_ * 16 + lr;
        float bias = bv[o];
        uint2 uu;
        uu.x = cvtpk(acc[n_][0] + bias, acc[n_][1] + bias);
        uu.y = cvtpk(acc[n_][2] + bias, acc[n_][3] + bias);
        *(uint2*)&vp[(size_t)o * WW + wid * 16 + lg * 4] = uu;
    }
}

// ---------------- K = dilated 3x3 conv (dilation 4, pad 4) over N -> [B,H,W,C] bf16
// 128-wide output tile; A via LDS, B direct global->reg (fragment-linear, L2-hot).
__global__ __launch_bounds__(256) void dconv_k(
    const unsigned short* __restrict__ ntl, const unsigned short* __restrict__ ntr,
    const unsigned short* __restrict__ wfr,
    const float* __restrict__ dlb, const float* __restrict__ drb,
    unsigned short* __restrict__ klo, unsigned short* __restrict__ kro)
{
    const int side = blockIdx.y;
    const unsigned short* nt = side ? ntr : ntl;
    const unsigned short* wbase = wfr + (size_t)side * 9 * 16384;
    const float* bd = side ? drb : dlb;
    unsigned short* ko = side ? kro : klo;
    // bijective XCD swizzle (1536 = 8*192): consecutive logical ids per XCD
    const int bid0 = blockIdx.x;
    const int lgc = (bid0 & 7) * 192 + (bid0 >> 3);
    const int wt = lgc & 3;
    const int hb = lgc >> 2;          // 0..383
    const int h = hb % HH, b = hb / HH;
    const int w0 = wt * 128;
    const int t = threadIdx.x;
    const int wid = t >> 6, l = t & 63, lr = l & 15, lg = l >> 4;
    const int whalf = wid & 1, ohalf = wid >> 1;

    __shared__ unsigned short sA[136][136];   // one dy-row of N, w0-4 .. w0+131

    f32x4 acc[4][4] = {};   // [g: w-subgroup][n: o-subgroup]
    for (int dy = 0; dy < 3; dy++) {
        const int hh = h + 4 * (dy - 1);
        const bool hok = (hh >= 0 && hh < HH);
        __syncthreads();
        for (int f = t * 8; f < 136 * 128; f += 2048) {
            int wloc = f >> 7, c = f & 127;
            int w = w0 - 4 + wloc;
            bf16x8 v = {0, 0, 0, 0, 0, 0, 0, 0};
            if (hok && w >= 0 && w < WW)
                v = *(const bf16x8*)(nt + ((size_t)(b * HH + hh) * WW + w) * CC + c);
            *(bf16x8*)&sA[wloc][c] = v;
        }
        __syncthreads();
#pragma unroll
        for (int dx = 0; dx < 3; dx++) {
            const unsigned short* wtap =
                wbase + (size_t)(dy * 3 + dx) * 16384 + ohalf * 8192 + l * 8;
#pragma unroll
            for (int kk = 0; kk < 4; kk++) {
                bf16x8 bfr[4];
#pragma unroll
                for (int n_ = 0; n_ < 4; n_++)
                    bfr[n_] = *(const bf16x8*)(wtap + (kk * 4 + n_) * 512);
                bf16x8 af[4];
#pragma unroll
                for (int g = 0; g < 4; g++)
                    af[g] = *(const bf16x8*)&sA[whalf * 64 + g * 16 + lr + 4 * dx][kk * 32 + lg * 8];
#pragma unroll
                for (int g = 0; g < 4; g++)
#pragma unroll
                    for (int n_ = 0; n_ < 4; n_++)
                        acc[g][n_] = MFMA(af[g], bfr[n_], acc[g][n_]);
            }
        }
    }
    unsigned short* kp = ko + ((size_t)(b * HH + h) * WW + w0) * CC;
    for (int g = 0; g < 4; g++)
        for (int n_ = 0; n_ < 4; n_++) {
            int o = ohalf * 64 + n_ * 16 + lr;
            float bias = bd[o];
            for (int j = 0; j < 4; j++) {
                int w = whalf * 64 + g * 16 + lg * 4 + j;
                kp[(size_t)w * CC + o] = f2bf(acc[g][n_][j] + bias);
            }
        }
}

// ---------------- fused Q-GEMM + flash attention (swapped-operand, QBLK=128)
// Double-buffered K/V LDS tiles: ONE barrier per KV tile, staging writes
// moved after PV (write-late). LDS 70 KB -> 2 blocks/CU (= measured occupancy).
__global__ __launch_bounds__(256, 2) void attn_k(
    const unsigned short* __restrict__ ntl, const unsigned short* __restrict__ ntr,
    const unsigned short* __restrict__ kl,  const unsigned short* __restrict__ kr,
    const unsigned short* __restrict__ vtl, const unsigned short* __restrict__ vtr,
    const float* __restrict__ lp1w, const float* __restrict__ lp1b,
    const float* __restrict__ rp1w, const float* __restrict__ rp1b,
    const float* __restrict__ xl, const float* __restrict__ xr,
    const float* __restrict__ beta, const float* __restrict__ gamma,
    float* __restrict__ out)
{
    __shared__ __align__(16) char smem[71680];
    // phase A: sQ = bytes 0..34816 (128 rows x 136), sWh = 34816..52224
    // phase B: K0 @ 0 (17408), K1 @ 17408, V0 @ 34816 (18432), V1 @ 53248
    unsigned short* sQ  = (unsigned short*)smem;
    unsigned short* sWh = (unsigned short*)(smem + 34816);

    const int dir = blockIdx.z;
    const unsigned short* nq  = dir ? ntr : ntl;
    const unsigned short* kws = dir ? kl : kr;
    const unsigned short* vws = dir ? vtl : vtr;
    const float* wq   = dir ? rp1w : lp1w;
    const float* bq   = dir ? rp1b : lp1b;
    const float* xres = dir ? xr : xl;
    const float* mult = dir ? gamma : beta;
    float* op = out + (size_t)dir * TENS;

    // XCD-locality swizzle: 4 q-blocks of one bh land consecutively on one XCD
    const int bid = blockIdx.x;
    const int xcd = bid & 7;
    const int s   = bid >> 3;         // 0..191
    const int qb  = s & 3;
    const int bh  = xcd + 8 * (s >> 2);   // 0..383
    const int q0  = qb * 128;
    const int t = threadIdx.x;
    const int wid = t >> 6, l = t & 63, lr = l & 15, lg = l >> 4;

    const unsigned short* ksrc = kws + (size_t)bh * WW * CC;          // [w][c]
    const unsigned short* vsrc = vws + (size_t)bh * CC * WW;          // [c][w]

    // ---- issue K/V tile-0 global loads early (T14) ----
    bf16x8 kreg[4], vreg[4];
#pragma unroll
    for (int it = 0; it < 4; it++) {
        int f = it * 2048 + t * 8;
        kreg[it] = *(const bf16x8*)(ksrc + f);
    }
#pragma unroll
    for (int it = 0; it < 4; it++) {
        int f = it * 2048 + t * 8;
        int c = f >> 6, k = f & 63;
        vreg[it] = *(const bf16x8*)(vsrc + (size_t)c * WW + k);
    }

    // ---- Phase A: stage N tile (128 q-rows); Wq in 2 halves of 64 rows ----
    {
        const unsigned short* nsrc = nq + ((size_t)bh * WW + q0) * CC;
        for (int it = 0; it < 8; it++) {
            int f = it * 2048 + t * 8;
            *(bf16x8*)&sQ[(f >> 7) * 136 + (f & 127)] = *(const bf16x8*)(nsrc + f);
        }
        for (int it = 0; it < 8; it++) {
            int f = it * 1024 + t * 4;
            int o = f >> 7, c = f & 127;
            float4 v = *(const float4*)(wq + o * CC + c);
            *(uint32_t*)&sWh[o * 136 + c]     = cvtpk(v.x, v.y);
            *(uint32_t*)&sWh[o * 136 + c + 2] = cvtpk(v.z, v.w);
        }
    }
    f32x4 qacc[2][8] = {};
    __syncthreads();
    for (int kk = 0; kk < 4; kk++) {
        bf16x8 a0 = *(const bf16x8*)&sQ[(wid * 32 + lr) * 136 + kk * 32 + lg * 8];
        bf16x8 a1 = *(const bf16x8*)&sQ[(wid * 32 + 16 + lr) * 136 + kk * 32 + lg * 8];
#pragma unroll
        for (int n_ = 0; n_ < 4; n_++) {
            bf16x8 b = *(const bf16x8*)&sWh[(n_ * 16 + lr) * 136 + kk * 32 + lg * 8];
            qacc[0][n_] = MFMA(a0, b, qacc[0][n_]);
            qacc[1][n_] = MFMA(a1, b, qacc[1][n_]);
        }
    }
    __syncthreads();
    for (int it = 0; it < 8; it++) {
        int f = it * 1024 + t * 4;
        int o = f >> 7, c = f & 127;
        float4 v = *(const float4*)(wq + (o + 64) * CC + c);
        *(uint32_t*)&sWh[o * 136 + c]     = cvtpk(v.x, v.y);
        *(uint32_t*)&sWh[o * 136 + c + 2] = cvtpk(v.z, v.w);
    }
    __syncthreads();
    for (int kk = 0; kk < 4; kk++) {
        bf16x8 a0 = *(const bf16x8*)&sQ[(wid * 32 + lr) * 136 + kk * 32 + lg * 8];
        bf16x8 a1 = *(const bf16x8*)&sQ[(wid * 32 + 16 + lr) * 136 + kk * 32 + lg * 8];
#pragma unroll
        for (int n_ = 0; n_ < 4; n_++) {
            bf16x8 b = *(const bf16x8*)&sWh[(n_ * 16 + lr) * 136 + kk * 32 + lg * 8];
            qacc[0][4 + n_] = MFMA(a0, b, qacc[0][4 + n_]);
            qacc[1][4 + n_] = MFMA(a1, b, qacc[1][4 + n_]);
        }
    }
    __syncthreads();   // all reads of sQ/sWh done before overwrite
    {
        const float SCL = 0.08838834764831845f * 1.4426950408889634f;  // C^-0.5 * log2e
#pragma unroll
        for (int mg = 0; mg < 2; mg++)
#pragma unroll
            for (int n_ = 0; n_ < 8; n_++) {
                float bias = bq[n_ * 16 + lr];
#pragma unroll
                for (int j = 0; j < 4; j++)
                    sQ[(wid * 32 + mg * 16 + lg * 4 + j) * 136 + n_ * 16 + lr] =
                        f2bf((qacc[mg][n_][j] + bias) * SCL);
            }
    }
    __syncthreads();
    bf16x8 qf[2][4];
#pragma unroll
    for (int qg = 0; qg < 2; qg++)
#pragma unroll
        for (int kk = 0; kk < 4; kk++)
            qf[qg][kk] = *(const bf16x8*)&sQ[(wid * 32 + qg * 16 + lr) * 136 + kk * 32 + lg * 8];

    __syncthreads();   // all qf reads done -> safe to overwrite sQ region with K0/V0

    // ---- prologue: write tile 0 into buffer 0 ----
    {
        unsigned short* dK = (unsigned short*)smem;             // K0
        unsigned short* dV = (unsigned short*)(smem + 34816);   // V0
#pragma unroll
        for (int it = 0; it < 4; it++) {
            int f = it * 2048 + t * 8;
            *(bf16x8*)&dK[(f >> 7) * 136 + (f & 127)] = kreg[it];
        }
#pragma unroll
        for (int it = 0; it < 4; it++) {
            int f = it * 2048 + t * 8;
            int c = f >> 6, k = f & 63;
            *(bf16x8*)&dV[c * 72 + k] = vreg[it];
        }
    }

    // ---- Phase B: online-softmax attention, swapped operands, double-buffered ----
    // lane holds P[k=n*16+lg*4+j][q=wid*32+qg*16+lr] -> row-local softmax per qg
    f32x4 oacc[8][2] = {};           // O^T[c=n*16+lg*4+j][q per qg]
    float mrow[2] = {-1e30f, -1e30f};
    float lrow[2] = {0.f, 0.f};

    for (int kb = 0; kb < 8; kb++) {
        const int cur = kb & 1;
        const unsigned short* sKt = (const unsigned short*)(smem + cur * 17408);
        const unsigned short* sVt = (const unsigned short*)(smem + 34816 + cur * 18432);
        __syncthreads();   // publishes buf[cur] writes; all waves done reading buf[cur^1]
        // issue next-tile loads (latency hidden under QK + softmax + PV)
        if (kb < 7) {
#pragma unroll
            for (int it = 0; it < 4; it++) {
                int f = it * 2048 + t * 8;
                kreg[it] = *(const bf16x8*)(ksrc + (kb + 1) * 64 * CC + f);
            }
#pragma unroll
            for (int it = 0; it < 4; it++) {
                int f = it * 2048 + t * 8;
                int c = f >> 6, k = f & 63;
                vreg[it] = *(const bf16x8*)(vsrc + (size_t)c * WW + (kb + 1) * 64 + k);
            }
        }
        // QK^T swapped: A = K rows (k), B = Q (col=q); kf read once per (kk,n_)
        f32x4 sacc[2][4] = {};
        __builtin_amdgcn_s_setprio(1);
        for (int kk = 0; kk < 4; kk++)
#pragma unroll
            for (int n_ = 0; n_ < 4; n_++) {
                bf16x8 kf = *(const bf16x8*)&sKt[(n_ * 16 + lr) * 136 + kk * 32 + lg * 8];
                sacc[0][n_] = MFMA(kf, qf[0][kk], sacc[0][n_]);
                sacc[1][n_] = MFMA(kf, qf[1][kk], sacc[1][n_]);
            }
        __builtin_amdgcn_s_setprio(0);
        // tile max per qg
        float pm[2];
#pragma unroll
        for (int qg = 0; qg < 2; qg++) {
            float m_ = sacc[qg][0][0];
#pragma unroll
            for (int n_ = 0; n_ < 4; n_++)
#pragma unroll
                for (int j = 0; j < 4; j++) m_ = fmaxf(m_, sacc[qg][n_][j]);
            m_ = fmaxf(m_, __shfl_xor(m_, 16, 64));
            m_ = fmaxf(m_, __shfl_xor(m_, 32, 64));
            pm[qg] = m_;
        }
        // defer-max (T13): only rescale when max grew by > 8 (log2 units)
        bool need = (pm[0] - mrow[0] > 8.f) || (pm[1] - mrow[1] > 8.f);
        if (__any(need)) {
            float al[2];
#pragma unroll
            for (int qg = 0; qg < 2; qg++) {
                float mn = fmaxf(mrow[qg], pm[qg]);
                al[qg] = exp2f(mrow[qg] - mn);
                mrow[qg] = mn;
                lrow[qg] *= al[qg];
            }
#pragma unroll
            for (int n_ = 0; n_ < 8; n_++)
#pragma unroll
                for (int qg = 0; qg < 2; qg++) {
                    f32x4 o = oacc[n_][qg];
                    o[0] *= al[qg]; o[1] *= al[qg]; o[2] *= al[qg]; o[3] *= al[qg];
                    oacc[n_][qg] = o;
                }
        }
        // exponentials + row-sum (in place: sacc becomes P)
#pragma unroll
        for (int qg = 0; qg < 2; qg++) {
            float rs = 0.f;
#pragma unroll
            for (int n_ = 0; n_ < 4; n_++)
#pragma unroll
                for (int j = 0; j < 4; j++) {
                    float e = exp2f(sacc[qg][n_][j] - mrow[qg]);
                    sacc[qg][n_][j] = e;
                    rs += e;
                }
            rs += __shfl_xor(rs, 16, 64);
            rs += __shfl_xor(rs, 32, 64);
            lrow[qg] += rs;
        }
        // PV via 16x16x16 MFMA: lane-local P fragment (k = n_*16 + lg*4 + j,
        // col = q = lr) IS the K=16 B-frag layout -> just cvtpk, no shuffle.
        __builtin_amdgcn_s_setprio(1);
#pragma unroll
        for (int n_ = 0; n_ < 4; n_++) {
            union { uint32_t u[2]; bf16x4 v; } b0, b1;
            b0.u[0] = cvtpk(sacc[0][n_][0], sacc[0][n_][1]);
            b0.u[1] = cvtpk(sacc[0][n_][2], sacc[0][n_][3]);
            b1.u[0] = cvtpk(sacc[1][n_][0], sacc[1][n_][1]);
            b1.u[1] = cvtpk(sacc[1][n_][2], sacc[1][n_][3]);
#pragma unroll
            for (int n8 = 0; n8 < 8; n8++) {
                bf16x4 va = *(const bf16x4*)&sVt[(n8 * 16 + lr) * 72 + n_ * 16 + lg * 4];
                oacc[n8][0] = MFMA16(va, b0.v, oacc[n8][0]);
                oacc[n8][1] = MFMA16(va, b1.v, oacc[n8][1]);
            }
        }
        __builtin_amdgcn_s_setprio(0);
        // write-late: stage next tile into the other buffer (disjoint region;
        // visibility to other waves via the barrier at top of next iteration)
        if (kb < 7) {
            unsigned short* dK = (unsigned short*)(smem + (cur ^ 1) * 17408);
            unsigned short* dV = (unsigned short*)(smem + 34816 + (cur ^ 1) * 18432);
#pragma unroll
            for (int it = 0; it < 4; it++) {
                int f = it * 2048 + t * 8;
                *(bf16x8*)&dK[(f >> 7) * 136 + (f & 127)] = kreg[it];
            }
#pragma unroll
            for (int it = 0; it < 4; it++) {
                int f = it * 2048 + t * 8;
                int c = f >> 6, k = f & 63;
                *(bf16x8*)&dV[c * 72 + k] = vreg[it];
            }
        }
    }

    // ---- epilogue: O^T layout is already [c][w] -> direct coalesced store ----
    const float inv0 = 1.f / lrow[0], inv1 = 1.f / lrow[1];
    const int b = bh / HH, h = bh % HH;
    const int w_0 = q0 + wid * 32 + lr;
    const float* xp0 = xres + (size_t)b * CHW + (size_t)h * WW + w_0;
    float* outp0 = op + (size_t)b * CHW + (size_t)h * WW + w_0;
#pragma unroll
    for (int n_ = 0; n_ < 8; n_++) {
        float4 m4 = *(const float4*)&mult[n_ * 16 + lg * 4];
#pragma unroll
        for (int j = 0; j < 4; j++) {
            int c = n_ * 16 + lg * 4 + j;
            float mj = (&m4.x)[j];
            outp0[(size_t)c * HW]      = xp0[(size_t)c * HW]      + oacc[n_][0][j] * inv0 * mj;
            outp0[(size_t)c * HW + 16] = xp0[(size_t)c * HW + 16] + oacc[n_][1][j] * inv1 * mj;
        }
    }
}

extern "C" void kernel_launch(void* const* d_in, const int* in_sizes, int n_in,
                              void* d_out, int out_size, void* d_ws, size_t ws_size,
                              hipStream_t stream)
{
    const float* xl   = (const float*)d_in[0];
    const float* xr   = (const float*)d_in[1];
    const float* nlw  = (const float*)d_in[2];
    const float* nlb  = (const float*)d_in[3];
    const float* nrw  = (const float*)d_in[4];
    const float* nrb  = (const float*)d_in[5];
    const float* lp1w = (const float*)d_in[6];
    const float* lp1b = (const float*)d_in[7];
    const float* rp1w = (const float*)d_in[8];
    const float* rp1b = (const float*)d_in[9];
    const float* dlw  = (const float*)d_in[10];
    const float* dlb  = (const float*)d_in[11];
    const float* drw  = (const float*)d_in[12];
    const float* drb  = (const float*)d_in[13];
    const float* lp2w = (const float*)d_in[14];
    const float* lp2b = (const float*)d_in[15];
    const float* rp2w = (const float*)d_in[16];
    const float* rp2b = (const float*)d_in[17];
    const float* beta = (const float*)d_in[18];
    const float* gamma= (const float*)d_in[19];
    float* out = (float*)d_out;

    unsigned short* ws = (unsigned short*)d_ws;
    const size_t A = (size_t)TENS;
    unsigned short* Ntl = ws;
    unsigned short* Ntr = ws + A;
    unsigned short* Kl  = ws + 2 * A;
    unsigned short* Kr  = ws + 3 * A;
    unsigned short* Vtl = ws + 4 * A;   // [B,H,C,W]
    unsigned short* Vtr = ws + 5 * A;
    unsigned short* Wd  = ws + 6 * A;   // fragment-linear dconv weights

    wcast_k<<<dim3(1152), 256, 0, stream>>>(dlw, drw, Wd);
    lnv_k<<<dim3(3072, 2), 256, 0, stream>>>(xl, xr, nlw, nlb, nrw, nrb,
        lp2w, lp2b, rp2w, rp2b, Ntl, Ntr, Vtl, Vtr);
    dconv_k<<<dim3(1536, 2), 256, 0, stream>>>(Ntl, Ntr, Wd, dlb, drb, Kl, Kr);
    attn_k<<<dim3(1536, 1, 2), 256, 0, stream>>>(Ntl, Ntr, Kl, Kr, Vtl, Vtr,
        lp1w, lp1b, rp1w, rp1b, xl, xr, beta, gamma, out);
}